// Round 1
// baseline (27349.100 us; speedup 1.0000x reference)
//
#include <hip/hip_runtime.h>
#include <math.h>

// ---- problem constants ----
#define BB 32
#define SS 197
#define DD 768
#define HH 12
#define DHD 64
#define LL 12
#define FF 3072
#define NPATCH 196
#define NTOK (BB * SS)          // 6304
#define LNEPS 1e-5f

// =====================================================================
// patchify: image [B,3,224,224] -> P [B*196, 768], order (c,pi,pj)
// =====================================================================
__global__ __launch_bounds__(256) void k_patchify(const float* __restrict__ img,
                                                  float* __restrict__ P) {
    const int total = BB * NPATCH * DD;
    for (int idx = blockIdx.x * 256 + threadIdx.x; idx < total; idx += gridDim.x * 256) {
        int e = idx % DD;
        int rest = idx / DD;
        int p = rest % NPATCH;
        int b = rest / NPATCH;
        int c = e >> 8;
        int pi = (e >> 4) & 15;
        int pj = e & 15;
        int i = p / 14, j = p % 14;
        P[idx] = img[(((size_t)b * 3 + c) * 224 + (i * 16 + pi)) * 224 + (j * 16 + pj)];
    }
}

// =====================================================================
// generic SGEMM: C[m,n] = act( sum_k A[m,k] * W[n,k] + bias[n] )  (+residual)
// A: [M,K] row-major; W: [N,K] row-major (i.e. C = A * W^T)
// REMAP: output row m -> (m/196)*197 + m%196 + 1   (embed -> x token slot)
// =====================================================================
template <int GELU, int RES, int REMAP>
__global__ __launch_bounds__(256) void k_gemm(const float* __restrict__ A,
                                              const float* __restrict__ W,
                                              const float* __restrict__ bias,
                                              float* __restrict__ C,
                                              int M, int N, int K) {
    __shared__ __align__(16) float As[16][68];
    __shared__ __align__(16) float Ws[16][68];
    const int tid = threadIdx.x;
    const int bm = blockIdx.y << 6, bn = blockIdx.x << 6;
    const int tm = (tid >> 4) << 2, tn = (tid & 15) << 2;
    float acc[4][4] = {{0.f}};

    const int lm = tid >> 2;            // 0..63
    const int lk = (tid & 3) << 2;      // 0,4,8,12
    const bool va = (bm + lm) < M;
    const bool vw = (bn + lm) < N;
    const float* Aptr = A + (size_t)(bm + lm) * K + lk;
    const float* Wptr = W + (size_t)(bn + lm) * K + lk;

    for (int k0 = 0; k0 < K; k0 += 16) {
        float4 a4 = va ? *(const float4*)(Aptr + k0) : make_float4(0.f, 0.f, 0.f, 0.f);
        float4 w4 = vw ? *(const float4*)(Wptr + k0) : make_float4(0.f, 0.f, 0.f, 0.f);
        As[lk + 0][lm] = a4.x; As[lk + 1][lm] = a4.y;
        As[lk + 2][lm] = a4.z; As[lk + 3][lm] = a4.w;
        Ws[lk + 0][lm] = w4.x; Ws[lk + 1][lm] = w4.y;
        Ws[lk + 2][lm] = w4.z; Ws[lk + 3][lm] = w4.w;
        __syncthreads();
#pragma unroll
        for (int kk = 0; kk < 16; ++kk) {
            float4 av = *(const float4*)&As[kk][tm];
            float4 wv = *(const float4*)&Ws[kk][tn];
            float a[4] = {av.x, av.y, av.z, av.w};
            float w[4] = {wv.x, wv.y, wv.z, wv.w};
#pragma unroll
            for (int i = 0; i < 4; ++i)
#pragma unroll
                for (int j = 0; j < 4; ++j) acc[i][j] += a[i] * w[j];
        }
        __syncthreads();
    }

#pragma unroll
    for (int i = 0; i < 4; ++i) {
        int gm = bm + tm + i;
        if (gm >= M) continue;
        size_t om = gm;
        if (REMAP) om = (size_t)(gm / 196) * 197 + (gm % 196) + 1;
#pragma unroll
        for (int j = 0; j < 4; ++j) {
            int gn = bn + tn + j;
            if (gn >= N) continue;
            float val = acc[i][j] + bias[gn];
            if (GELU) val = 0.5f * val * (1.f + erff(val * 0.7071067811865476f));
            float* dst = C + om * (size_t)N + gn;
            if (RES) *dst += val; else *dst = val;
        }
    }
}

// =====================================================================
// pos-embed add (+cls for s==0). x[b,s,d] (+)= pos(s,d)
// =====================================================================
__global__ __launch_bounds__(256) void k_posadd(float* __restrict__ x,
                                                const float* __restrict__ cls) {
    const int total = BB * SS * DD;
    const float LN1E4 = 9.210340371976184f;  // ln(10000)
    for (int idx = blockIdx.x * 256 + threadIdx.x; idx < total; idx += gridDim.x * 256) {
        int d = idx % DD;
        int s = (idx / DD) % SS;
        float ang = (float)s * expf(-LN1E4 * (float)(2 * (d >> 1)) / 768.f);
        float pv = (d & 1) ? cosf(ang) : sinf(ang);
        if (s == 0) x[idx] = cls[d] + pv;
        else        x[idx] += pv;
    }
}

// =====================================================================
// LayerNorm per token row: out = (x-mean)*rstd*g + b
// =====================================================================
__global__ __launch_bounds__(256) void k_layernorm(const float* __restrict__ x,
                                                   const float* __restrict__ g,
                                                   const float* __restrict__ bparm,
                                                   float* __restrict__ out) {
    const int row = blockIdx.x;
    const int tid = threadIdx.x;
    __shared__ float xs[DD];
    __shared__ float red[8];
    const float* xr = x + (size_t)row * DD;

    float s = 0.f;
    for (int d = tid; d < DD; d += 256) { float t = xr[d]; xs[d] = t; s += t; }
#pragma unroll
    for (int o = 32; o; o >>= 1) s += __shfl_down(s, o);
    if ((tid & 63) == 0) red[tid >> 6] = s;
    __syncthreads();
    if (tid == 0) red[4] = (red[0] + red[1] + red[2] + red[3]) * (1.f / DD);
    __syncthreads();
    float mean = red[4];

    float v = 0.f;
    for (int d = tid; d < DD; d += 256) { float t = xs[d] - mean; v += t * t; }
#pragma unroll
    for (int o = 32; o; o >>= 1) v += __shfl_down(v, o);
    if ((tid & 63) == 0) red[tid >> 6] = v;
    __syncthreads();
    if (tid == 0) red[5] = 1.f / sqrtf(red[0] + red[1] + red[2] + red[3] != 0.f ?
                                       (red[0] + red[1] + red[2] + red[3]) * (1.f / DD) + LNEPS
                                       : LNEPS);
    __syncthreads();
    float rstd = red[5];

    for (int d = tid; d < DD; d += 256)
        out[(size_t)row * DD + d] = (xs[d] - mean) * rstd * g[d] + bparm[d];
}

// =====================================================================
// QKV: per head 64x64 projections. h [NTOK,768] -> q,k,v [NTOK,768]
// 8 tokens per block.
// =====================================================================
__global__ __launch_bounds__(256) void k_qkv(const float* __restrict__ h,
                                             const float* __restrict__ Wq, const float* __restrict__ bq,
                                             const float* __restrict__ Wk, const float* __restrict__ bk,
                                             const float* __restrict__ Wv, const float* __restrict__ bv,
                                             float* __restrict__ q, float* __restrict__ k,
                                             float* __restrict__ v) {
    __shared__ __align__(16) float hs[8][DD];
    const int t0 = blockIdx.x * 8;
    const int tid = threadIdx.x;
    for (int l = tid; l < 8 * DD; l += 256) {
        int t = l / DD, d = l % DD;
        int gt = t0 + t;
        hs[t][d] = (gt < NTOK) ? h[(size_t)gt * DD + d] : 0.f;
    }
    __syncthreads();
    for (int oi = tid; oi < 8 * DD; oi += 256) {
        int t = oi / DD, hd = oi % DD;
        int gt = t0 + t;
        if (gt >= NTOK) continue;
        int head = hd >> 6, e = hd & 63;
        const float4* hv4 = (const float4*)&hs[t][head << 6];
        const float4* wq4 = (const float4*)(Wq + (size_t)(((head << 6) + e) << 6));
        const float4* wk4 = (const float4*)(Wk + (size_t)(((head << 6) + e) << 6));
        const float4* wv4 = (const float4*)(Wv + (size_t)(((head << 6) + e) << 6));
        float aq = 0.f, ak = 0.f, av = 0.f;
#pragma unroll
        for (int d4 = 0; d4 < 16; ++d4) {
            float4 hx = hv4[d4];
            float4 a = wq4[d4];
            float4 bq4 = wk4[d4];
            float4 c = wv4[d4];
            aq += hx.x * a.x + hx.y * a.y + hx.z * a.z + hx.w * a.w;
            ak += hx.x * bq4.x + hx.y * bq4.y + hx.z * bq4.z + hx.w * bq4.w;
            av += hx.x * c.x + hx.y * c.y + hx.z * c.z + hx.w * c.w;
        }
        size_t oidx = (size_t)gt * DD + hd;
        q[oidx] = aq + bq[hd];
        k[oidx] = ak + bk[hd];
        v[oidx] = av + bv[hd];
    }
}

// =====================================================================
// attention, one (b, head, query-row) per block; fused residual add into x
// =====================================================================
__global__ __launch_bounds__(256) void k_attn(const float* __restrict__ q,
                                              const float* __restrict__ k,
                                              const float* __restrict__ v,
                                              float* __restrict__ x) {
    const int sr = blockIdx.x, head = blockIdx.y, b = blockIdx.z;
    const int tid = threadIdx.x;
    __shared__ float qrow[DHD];
    __shared__ float sc[SS];
    __shared__ float part[4][DHD];
    __shared__ float red[8];
    const size_t base = (size_t)b * SS * DD + (head << 6);

    if (tid < DHD) qrow[tid] = q[base + (size_t)sr * DD + tid];
    __syncthreads();

    float mx = -1e30f;
    for (int t = tid; t < SS; t += 256) {
        const float4* kr = (const float4*)(k + base + (size_t)t * DD);
        float d0 = 0.f;
#pragma unroll
        for (int e4 = 0; e4 < 16; ++e4) {
            float4 kk4 = kr[e4];
            const float4* q4 = (const float4*)&qrow[e4 << 2];
            float4 qq = *q4;
            d0 += qq.x * kk4.x + qq.y * kk4.y + qq.z * kk4.z + qq.w * kk4.w;
        }
        d0 *= 0.125f;
        sc[t] = d0;
        mx = fmaxf(mx, d0);
    }
#pragma unroll
    for (int o = 32; o; o >>= 1) mx = fmaxf(mx, __shfl_down(mx, o));
    if ((tid & 63) == 0) red[tid >> 6] = mx;
    __syncthreads();
    if (tid == 0) red[4] = fmaxf(fmaxf(red[0], red[1]), fmaxf(red[2], red[3]));
    __syncthreads();
    mx = red[4];

    float sum = 0.f;
    for (int t = tid; t < SS; t += 256) { float p = expf(sc[t] - mx); sc[t] = p; sum += p; }
#pragma unroll
    for (int o = 32; o; o >>= 1) sum += __shfl_down(sum, o);
    if ((tid & 63) == 0) red[tid >> 6] = sum;
    __syncthreads();
    if (tid == 0) red[5] = red[0] + red[1] + red[2] + red[3];
    __syncthreads();
    const float inv = 1.f / red[5];

    const int e = tid & 63, gidx = tid >> 6;
    float acc = 0.f;
    for (int t = gidx; t < SS; t += 4)
        acc += sc[t] * v[base + (size_t)t * DD + e];
    part[gidx][e] = acc;
    __syncthreads();
    if (tid < DHD) {
        float o4 = (part[0][tid] + part[1][tid] + part[2][tid] + part[3][tid]) * inv;
        x[base + (size_t)sr * DD + tid] += o4;
    }
}

// =====================================================================
// classifier head: out[b,c] = x[b,0,:] . Wh[c,:] + bh[c]
// =====================================================================
__global__ __launch_bounds__(256) void k_head(const float* __restrict__ x,
                                              const float* __restrict__ Wh,
                                              const float* __restrict__ bh,
                                              float* __restrict__ out) {
    const int b = blockIdx.y;
    const int c = blockIdx.x * 256 + threadIdx.x;
    __shared__ __align__(16) float xs[DD];
    const float* xr = x + (size_t)b * SS * DD;
    for (int d = threadIdx.x; d < DD; d += 256) xs[d] = xr[d];
    __syncthreads();
    if (c < 1000) {
        const float4* w4 = (const float4*)(Wh + (size_t)c * DD);
        float acc = 0.f;
#pragma unroll 4
        for (int d4 = 0; d4 < DD / 4; ++d4) {
            float4 w = w4[d4];
            const float4 xv = *(const float4*)&xs[d4 << 2];
            acc += xv.x * w.x + xv.y * w.y + xv.z * w.z + xv.w * w.w;
        }
        out[(size_t)b * 1000 + c] = acc + bh[c];
    }
}

// =====================================================================
extern "C" void kernel_launch(void* const* d_in, const int* in_sizes, int n_in,
                              void* d_out, int out_size, void* d_ws, size_t ws_size,
                              hipStream_t stream) {
    const float* image   = (const float*)d_in[0];
    const float* W_embed = (const float*)d_in[1];
    const float* b_embed = (const float*)d_in[2];
    const float* cls     = (const float*)d_in[3];
    const float* Wq      = (const float*)d_in[4];
    const float* bq      = (const float*)d_in[5];
    const float* Wk      = (const float*)d_in[6];
    const float* bk      = (const float*)d_in[7];
    const float* Wv      = (const float*)d_in[8];
    const float* bv      = (const float*)d_in[9];
    const float* ln1g    = (const float*)d_in[10];
    const float* ln1b    = (const float*)d_in[11];
    const float* ln2g    = (const float*)d_in[12];
    const float* ln2b    = (const float*)d_in[13];
    const float* W1      = (const float*)d_in[14];
    const float* b1      = (const float*)d_in[15];
    const float* W2      = (const float*)d_in[16];
    const float* b2      = (const float*)d_in[17];
    const float* Wh      = (const float*)d_in[18];
    const float* bh      = (const float*)d_in[19];
    float* out = (float*)d_out;

    const size_t BSD = (size_t)NTOK * DD;   // 4,841,472 floats
    float* x    = (float*)d_ws;
    float* h    = x + BSD;
    float* q    = h + BSD;
    float* kbuf = q + BSD;
    float* vbuf = kbuf + BSD;
    float* mlp  = vbuf + BSD;               // B*S*3072 floats
    float* P    = mlp;                      // alias: patches used only pre-layers

    // embed
    k_patchify<<<1024, 256, 0, stream>>>(image, P);
    k_gemm<0, 0, 1><<<dim3(12, 98), 256, 0, stream>>>(P, W_embed, b_embed, x,
                                                      BB * NPATCH, DD, DD);
    k_posadd<<<1024, 256, 0, stream>>>(x, cls);

    for (int l = 0; l < LL; ++l) {
        const float* Wq_l = Wq + (size_t)l * HH * DHD * DHD;
        const float* Wk_l = Wk + (size_t)l * HH * DHD * DHD;
        const float* Wv_l = Wv + (size_t)l * HH * DHD * DHD;
        k_layernorm<<<NTOK, 256, 0, stream>>>(x, ln1g + l * DD, ln1b + l * DD, h);
        k_qkv<<<(NTOK + 7) / 8, 256, 0, stream>>>(h, Wq_l, bq + l * DD, Wk_l, bk + l * DD,
                                                  Wv_l, bv + l * DD, q, kbuf, vbuf);
        k_attn<<<dim3(SS, HH, BB), 256, 0, stream>>>(q, kbuf, vbuf, x);
        k_layernorm<<<NTOK, 256, 0, stream>>>(x, ln2g + l * DD, ln2b + l * DD, h);
        k_gemm<1, 0, 0><<<dim3(FF / 64, (NTOK + 63) / 64), 256, 0, stream>>>(
            h, W1 + (size_t)l * FF * DD, b1 + (size_t)l * FF, mlp, NTOK, FF, DD);
        k_gemm<0, 1, 0><<<dim3(DD / 64, (NTOK + 63) / 64), 256, 0, stream>>>(
            mlp, W2 + (size_t)l * DD * FF, b2 + (size_t)l * DD, x, NTOK, DD, FF);
    }

    k_head<<<dim3(4, BB), 256, 0, stream>>>(x, Wh, bh, out);
}

// Round 2
// 12796.620 us; speedup vs baseline: 2.1372x; 2.1372x over previous
//
#include <hip/hip_runtime.h>
#include <math.h>

// ---- problem constants ----
#define BB 32
#define SS 197
#define DD 768
#define HH 12
#define DHD 64
#define LL 12
#define FF 3072
#define NPATCH 196
#define NTOK (BB * SS)          // 6304
#define MPAD 6400               // NTOK padded to multiple of 128
#define LNEPS 1e-5f

typedef short bf8_t __attribute__((ext_vector_type(8)));
typedef float f4_t  __attribute__((ext_vector_type(4)));

__device__ __forceinline__ unsigned short f2bf(float x) {
    unsigned u = __float_as_uint(x);
    return (unsigned short)((u + 0x8000u) >> 16);
}
__device__ __forceinline__ float bf_lo(unsigned u) { return __uint_as_float(u << 16); }
__device__ __forceinline__ float bf_hi(unsigned u) { return __uint_as_float(u & 0xffff0000u); }

__device__ __forceinline__ void gl_lds16(const void* g, void* l) {
    __builtin_amdgcn_global_load_lds((const __attribute__((address_space(1))) unsigned int*)g,
                                     (__attribute__((address_space(3))) unsigned int*)l, 16, 0, 0);
}

// =====================================================================
// fp32 -> bf16 converter (weights)
// =====================================================================
__global__ __launch_bounds__(256) void k_conv(const float* __restrict__ a,
                                              unsigned short* __restrict__ o, int n4) {
    for (int i = blockIdx.x * 256 + threadIdx.x; i < n4; i += gridDim.x * 256) {
        float4 v = ((const float4*)a)[i];
        ushort4 r;
        r.x = f2bf(v.x); r.y = f2bf(v.y); r.z = f2bf(v.z); r.w = f2bf(v.w);
        ((ushort4*)o)[i] = r;
    }
}

// =====================================================================
// patchify: image [B,3,224,224] -> P_bf [B*196, 768] bf16, order (c,pi,pj)
// =====================================================================
__global__ __launch_bounds__(256) void k_patchify(const float* __restrict__ img,
                                                  unsigned short* __restrict__ P) {
    const int total = BB * NPATCH * DD;
    for (int idx = blockIdx.x * 256 + threadIdx.x; idx < total; idx += gridDim.x * 256) {
        int e = idx % DD;
        int rest = idx / DD;
        int p = rest % NPATCH;
        int b = rest / NPATCH;
        int c = e >> 8;
        int pi = (e >> 4) & 15;
        int pj = e & 15;
        int i = p / 14, j = p % 14;
        P[idx] = f2bf(img[(((size_t)b * 3 + c) * 224 + (i * 16 + pi)) * 224 + (j * 16 + pj)]);
    }
}

// =====================================================================
// bf16 MFMA GEMM (m97 structure): C[m,n] = A[m,k] * W[n,k]^T + bias
// 128x128 tile, BK=32, 256 threads = 4 waves, each wave 64x64 via 4x4
// mfma_f32_16x16x32_bf16.  EPI: 0 = embed (remap rows, f32 store to x)
//                               1 = GELU -> bf16 store
//                               2 = residual add into f32 x
// =====================================================================
template <int EPI>
__global__ __launch_bounds__(256) void k_gemm_bf(const unsigned short* __restrict__ A,
                                                 const unsigned short* __restrict__ Bw,
                                                 const float* __restrict__ bias,
                                                 void* __restrict__ Cout,
                                                 int M, int N, int K) {
    __shared__ unsigned short As[128 * 32];
    __shared__ unsigned short Bs[128 * 32];
    const int tid = threadIdx.x;
    const int wave = tid >> 6, lane = tid & 63;
    const int m0 = blockIdx.y << 7, n0 = blockIdx.x << 7;

    // staging: chunk c covers row c>>2, k-part (c&3)*8 (16B)
    const int r0 = tid >> 2, kp = (tid & 3) * 8;
    const unsigned short* gA0 = A + (size_t)(m0 + r0) * K + kp;
    const unsigned short* gA1 = A + (size_t)(m0 + 64 + r0) * K + kp;
    const unsigned short* gB0 = Bw + (size_t)(n0 + r0) * K + kp;
    const unsigned short* gB1 = Bw + (size_t)(n0 + 64 + r0) * K + kp;
    unsigned short* lA0 = &As[tid * 8];
    unsigned short* lA1 = &As[(tid + 256) * 8];
    unsigned short* lB0 = &Bs[tid * 8];
    unsigned short* lB1 = &Bs[(tid + 256) * 8];

    const int mh = (wave >> 1) << 6, nh = (wave & 1) << 6;
    const int lm = lane & 15, kq = lane >> 4;

    f4_t acc[4][4];
#pragma unroll
    for (int i = 0; i < 4; ++i)
#pragma unroll
        for (int j = 0; j < 4; ++j) acc[i][j] = (f4_t){0.f, 0.f, 0.f, 0.f};

    for (int k0 = 0; k0 < K; k0 += 32) {
        gl_lds16(gA0, lA0);
        gl_lds16(gA1, lA1);
        gl_lds16(gB0, lB0);
        gl_lds16(gB1, lB1);
        gA0 += 32; gA1 += 32; gB0 += 32; gB1 += 32;
        __syncthreads();
        bf8_t af[4], bfr[4];
#pragma unroll
        for (int mt = 0; mt < 4; ++mt)
            af[mt] = *(const bf8_t*)&As[(mh + mt * 16 + lm) * 32 + kq * 8];
#pragma unroll
        for (int nt = 0; nt < 4; ++nt)
            bfr[nt] = *(const bf8_t*)&Bs[(nh + nt * 16 + lm) * 32 + kq * 8];
#pragma unroll
        for (int mt = 0; mt < 4; ++mt)
#pragma unroll
            for (int nt = 0; nt < 4; ++nt)
                acc[mt][nt] = __builtin_amdgcn_mfma_f32_16x16x32_bf16(af[mt], bfr[nt],
                                                                      acc[mt][nt], 0, 0, 0);
        __syncthreads();
    }

    // epilogue: row = m0+mh+mt*16+kq*4+r, col = n0+nh+nt*16+lm
    const int rbase = m0 + mh + kq * 4;
    const int cbase = n0 + nh + lm;
#pragma unroll
    for (int mt = 0; mt < 4; ++mt) {
#pragma unroll
        for (int nt = 0; nt < 4; ++nt) {
            const int col = cbase + nt * 16;
            const float bv = bias[col];
#pragma unroll
            for (int r = 0; r < 4; ++r) {
                const int row = rbase + mt * 16 + r;
                float val = acc[mt][nt][r] + bv;
                if (EPI == 0) {
                    // embed: remap row (per-batch 196 -> token slot +1), write f32 x
                    size_t om = (size_t)(row / 196) * 197 + (row % 196) + 1;
                    ((float*)Cout)[om * DD + col] = val;
                } else if (EPI == 1) {
                    val = 0.5f * val * (1.f + erff(val * 0.7071067811865476f));
                    ((unsigned short*)Cout)[(size_t)row * N + col] = f2bf(val);
                } else {
                    if (row < M) ((float*)Cout)[(size_t)row * DD + col] += val;
                }
            }
        }
    }
}

// =====================================================================
// pos-embed add (+cls for s==0)
// =====================================================================
__global__ __launch_bounds__(256) void k_posadd(float* __restrict__ x,
                                                const float* __restrict__ cls) {
    const int total = BB * SS * DD;
    const float LN1E4 = 9.210340371976184f;
    for (int idx = blockIdx.x * 256 + threadIdx.x; idx < total; idx += gridDim.x * 256) {
        int d = idx % DD;
        int s = (idx / DD) % SS;
        float ang = (float)s * __expf(-LN1E4 * (float)(2 * (d >> 1)) / 768.f);
        float pv = (d & 1) ? __cosf(ang) : __sinf(ang);
        if (s == 0) x[idx] = cls[d] + pv;
        else        x[idx] += pv;
    }
}

// =====================================================================
// LayerNorm; BF=0 -> f32 out (for QKV), BF=1 -> bf16 out (for MLP GEMM)
// =====================================================================
template <int BF>
__global__ __launch_bounds__(256) void k_ln(const float* __restrict__ x,
                                            const float* __restrict__ g,
                                            const float* __restrict__ bp,
                                            float* __restrict__ outf,
                                            unsigned short* __restrict__ outb) {
    const int row = blockIdx.x, tid = threadIdx.x;
    __shared__ float xs[DD];
    __shared__ float wsum[4];
    const float* xr = x + (size_t)row * DD;

    float s = 0.f;
    for (int d = tid; d < DD; d += 256) { float t = xr[d]; xs[d] = t; s += t; }
#pragma unroll
    for (int o = 32; o; o >>= 1) s += __shfl_xor(s, o);
    if ((tid & 63) == 0) wsum[tid >> 6] = s;
    __syncthreads();
    const float mean = (wsum[0] + wsum[1] + wsum[2] + wsum[3]) * (1.f / DD);

    float v = 0.f;
    for (int d = tid; d < DD; d += 256) { float t = xs[d] - mean; v += t * t; }
#pragma unroll
    for (int o = 32; o; o >>= 1) v += __shfl_xor(v, o);
    __syncthreads();
    if ((tid & 63) == 0) wsum[tid >> 6] = v;
    __syncthreads();
    const float rstd = rsqrtf((wsum[0] + wsum[1] + wsum[2] + wsum[3]) * (1.f / DD) + LNEPS);

    for (int d = tid; d < DD; d += 256) {
        float y = (xs[d] - mean) * rstd * g[d] + bp[d];
        if (BF) outb[(size_t)row * DD + d] = f2bf(y);
        else    outf[(size_t)row * DD + d] = y;
    }
}

// =====================================================================
// QKV (fp32, unchanged structure)
// =====================================================================
__global__ __launch_bounds__(256) void k_qkv(const float* __restrict__ h,
                                             const float* __restrict__ Wq, const float* __restrict__ bq,
                                             const float* __restrict__ Wk, const float* __restrict__ bk,
                                             const float* __restrict__ Wv, const float* __restrict__ bv,
                                             float* __restrict__ q, float* __restrict__ k,
                                             float* __restrict__ v) {
    __shared__ __align__(16) float hs[8][DD];
    const int t0 = blockIdx.x * 8;
    const int tid = threadIdx.x;
    for (int l = tid; l < 8 * DD; l += 256) {
        int t = l / DD, d = l % DD;
        int gt = t0 + t;
        hs[t][d] = (gt < NTOK) ? h[(size_t)gt * DD + d] : 0.f;
    }
    __syncthreads();
    for (int oi = tid; oi < 8 * DD; oi += 256) {
        int t = oi / DD, hd = oi % DD;
        int gt = t0 + t;
        if (gt >= NTOK) continue;
        int head = hd >> 6, e = hd & 63;
        const float4* hv4 = (const float4*)&hs[t][head << 6];
        const float4* wq4 = (const float4*)(Wq + (size_t)(((head << 6) + e) << 6));
        const float4* wk4 = (const float4*)(Wk + (size_t)(((head << 6) + e) << 6));
        const float4* wv4 = (const float4*)(Wv + (size_t)(((head << 6) + e) << 6));
        float aq = 0.f, ak = 0.f, av = 0.f;
#pragma unroll
        for (int d4 = 0; d4 < 16; ++d4) {
            float4 hx = hv4[d4];
            float4 a = wq4[d4];
            float4 b4 = wk4[d4];
            float4 c = wv4[d4];
            aq += hx.x * a.x + hx.y * a.y + hx.z * a.z + hx.w * a.w;
            ak += hx.x * b4.x + hx.y * b4.y + hx.z * b4.z + hx.w * b4.w;
            av += hx.x * c.x + hx.y * c.y + hx.z * c.z + hx.w * c.w;
        }
        size_t oidx = (size_t)gt * DD + hd;
        q[oidx] = aq + bq[hd];
        k[oidx] = ak + bk[hd];
        v[oidx] = av + bv[hd];
    }
}

// =====================================================================
// attention v2: block = (16 queries, head, b), 128 thr = 2 waves x 8 queries.
// K,V staged once to LDS (bf16): Kt[e][t] for scores, Vs[t][e] for PV.
// Each LDS read feeds 8..32 FMAs (register tiling over queries).
// =====================================================================
__global__ __launch_bounds__(128) void k_attn2(const float* __restrict__ qg,
                                               const float* __restrict__ kg,
                                               const float* __restrict__ vg,
                                               float* __restrict__ x) {
    const int qb = blockIdx.x, head = blockIdx.y, b = blockIdx.z;
    const int tid = threadIdx.x, wave = tid >> 6, lane = tid & 63;
    const size_t base = (size_t)b * SS * DD + (head << 6);

    __shared__ unsigned short Kt[64][200];   // [e][t], t padded to 200
    __shared__ unsigned short Vs[SS][64];    // [t][e]
    __shared__ float qs[2][64][8];           // [wave][e][i]
    __shared__ unsigned ps[2][50][20];       // [wave][t4][j*4+i2] bf16-pairs, row padded to 20

    // ---- stage K,V ----
    for (int idx = tid; idx < SS * DHD; idx += 128) {
        int t = idx >> 6, e = idx & 63;
        float kvk = kg[base + (size_t)t * DD + e];
        float kvv = vg[base + (size_t)t * DD + e];
        Kt[e][t] = f2bf(kvk);
        Vs[t][e] = f2bf(kvv);
    }
    if (tid < 192) { int t = SS + tid / 64, e = tid % 64; Kt[e][t] = 0; }

    // ---- stage q (8 per wave) ----
    const int q0 = qb * 16 + wave * 8;
#pragma unroll
    for (int i = 0; i < 8; ++i) {
        int sr = q0 + i;
        qs[wave][lane][i] = (sr < SS) ? qg[base + (size_t)sr * DD + lane] : 0.f;
    }
    __syncthreads();

    // ---- scores: lane l covers keys t = 4l..4l+3 ----
    float sc[8][4];
#pragma unroll
    for (int i = 0; i < 8; ++i)
#pragma unroll
        for (int j = 0; j < 4; ++j) sc[i][j] = 0.f;

    if (lane < 50) {
        const unsigned* K2 = (const unsigned*)Kt;   // rows of 100 dwords
        for (int e = 0; e < 64; ++e) {
            f4_t qa = *(const f4_t*)&qs[wave][e][0];
            f4_t qb4 = *(const f4_t*)&qs[wave][e][4];
            uint2 kk = *(const uint2*)&K2[e * 100 + (lane << 1)];
            float k0 = bf_lo(kk.x), k1 = bf_hi(kk.x), k2 = bf_lo(kk.y), k3 = bf_hi(kk.y);
#pragma unroll
            for (int i = 0; i < 4; ++i) {
                sc[i][0] += qa[i] * k0; sc[i][1] += qa[i] * k1;
                sc[i][2] += qa[i] * k2; sc[i][3] += qa[i] * k3;
                sc[i + 4][0] += qb4[i] * k0; sc[i + 4][1] += qb4[i] * k1;
                sc[i + 4][2] += qb4[i] * k2; sc[i + 4][3] += qb4[i] * k3;
            }
        }
    }

    // ---- softmax (per query, across wave) ----
    float inv[8];
#pragma unroll
    for (int i = 0; i < 8; ++i) {
        float s0 = sc[i][0] * 0.125f, s1 = sc[i][1] * 0.125f;
        float s2 = sc[i][2] * 0.125f, s3 = sc[i][3] * 0.125f;
        int t0 = lane << 2;
        if (t0 + 0 >= SS) s0 = -1e30f;
        if (t0 + 1 >= SS) s1 = -1e30f;
        if (t0 + 2 >= SS) s2 = -1e30f;
        if (t0 + 3 >= SS) s3 = -1e30f;
        float m = fmaxf(fmaxf(s0, s1), fmaxf(s2, s3));
#pragma unroll
        for (int o = 32; o; o >>= 1) m = fmaxf(m, __shfl_xor(m, o));
        float p0 = __expf(s0 - m), p1 = __expf(s1 - m);
        float p2 = __expf(s2 - m), p3 = __expf(s3 - m);
        float sm = p0 + p1 + p2 + p3;
#pragma unroll
        for (int o = 32; o; o >>= 1) sm += __shfl_xor(sm, o);
        inv[i] = 1.f / sm;
        sc[i][0] = p0; sc[i][1] = p1; sc[i][2] = p2; sc[i][3] = p3;
    }

    // ---- store p as bf16 pairs: ps[wave][t4=lane][j*4+i2] = (p[2*i2+1],p[2*i2]) ----
    if (lane < 50) {
#pragma unroll
        for (int j = 0; j < 4; ++j)
#pragma unroll
            for (int i2 = 0; i2 < 4; ++i2) {
                unsigned pa = (__float_as_uint(sc[2 * i2][j]) + 0x8000u) >> 16;
                unsigned pb = (__float_as_uint(sc[2 * i2 + 1][j]) + 0x8000u) & 0xffff0000u;
                ps[wave][lane][j * 4 + i2] = pa | pb;
            }
    }
    __syncthreads();

    // ---- PV: lane = e, accumulate 8 query outputs ----
    float out[8] = {0.f, 0.f, 0.f, 0.f, 0.f, 0.f, 0.f, 0.f};
    for (int t4 = 0; t4 < 49; ++t4) {
#pragma unroll
        for (int j = 0; j < 4; ++j) {
            float vv = bf_lo((unsigned)Vs[t4 * 4 + j][lane]);
            uint4 pp = *(const uint4*)&ps[wave][t4][j * 4];
            out[0] += bf_lo(pp.x) * vv; out[1] += bf_hi(pp.x) * vv;
            out[2] += bf_lo(pp.y) * vv; out[3] += bf_hi(pp.y) * vv;
            out[4] += bf_lo(pp.z) * vv; out[5] += bf_hi(pp.z) * vv;
            out[6] += bf_lo(pp.w) * vv; out[7] += bf_hi(pp.w) * vv;
        }
    }
    {   // t = 196 (t4 = 49, j = 0)
        float vv = bf_lo((unsigned)Vs[196][lane]);
        uint4 pp = *(const uint4*)&ps[wave][49][0];
        out[0] += bf_lo(pp.x) * vv; out[1] += bf_hi(pp.x) * vv;
        out[2] += bf_lo(pp.y) * vv; out[3] += bf_hi(pp.y) * vv;
        out[4] += bf_lo(pp.z) * vv; out[5] += bf_hi(pp.z) * vv;
        out[6] += bf_lo(pp.w) * vv; out[7] += bf_hi(pp.w) * vv;
    }

    // ---- residual add into x ----
#pragma unroll
    for (int i = 0; i < 8; ++i) {
        int sr = q0 + i;
        if (sr < SS) x[base + (size_t)sr * DD + lane] += out[i] * inv[i];
    }
}

// =====================================================================
// classifier head (fp32)
// =====================================================================
__global__ __launch_bounds__(256) void k_head(const float* __restrict__ x,
                                              const float* __restrict__ Wh,
                                              const float* __restrict__ bh,
                                              float* __restrict__ out) {
    const int b = blockIdx.y;
    const int c = blockIdx.x * 256 + threadIdx.x;
    __shared__ __align__(16) float xs[DD];
    const float* xr = x + (size_t)b * SS * DD;
    for (int d = threadIdx.x; d < DD; d += 256) xs[d] = xr[d];
    __syncthreads();
    if (c < 1000) {
        const float4* w4 = (const float4*)(Wh + (size_t)c * DD);
        float acc = 0.f;
#pragma unroll 4
        for (int d4 = 0; d4 < DD / 4; ++d4) {
            float4 w = w4[d4];
            const float4 xv = *(const float4*)&xs[d4 << 2];
            acc += xv.x * w.x + xv.y * w.y + xv.z * w.z + xv.w * w.w;
        }
        out[(size_t)b * 1000 + c] = acc + bh[c];
    }
}

// =====================================================================
extern "C" void kernel_launch(void* const* d_in, const int* in_sizes, int n_in,
                              void* d_out, int out_size, void* d_ws, size_t ws_size,
                              hipStream_t stream) {
    const float* image   = (const float*)d_in[0];
    const float* W_embed = (const float*)d_in[1];
    const float* b_embed = (const float*)d_in[2];
    const float* cls     = (const float*)d_in[3];
    const float* Wq      = (const float*)d_in[4];
    const float* bq      = (const float*)d_in[5];
    const float* Wk      = (const float*)d_in[6];
    const float* bk      = (const float*)d_in[7];
    const float* Wv      = (const float*)d_in[8];
    const float* bv      = (const float*)d_in[9];
    const float* ln1g    = (const float*)d_in[10];
    const float* ln1b    = (const float*)d_in[11];
    const float* ln2g    = (const float*)d_in[12];
    const float* ln2b    = (const float*)d_in[13];
    const float* W1      = (const float*)d_in[14];
    const float* b1      = (const float*)d_in[15];
    const float* W2      = (const float*)d_in[16];
    const float* b2      = (const float*)d_in[17];
    const float* Wh      = (const float*)d_in[18];
    const float* bh      = (const float*)d_in[19];
    float* out = (float*)d_out;

    const size_t BSD = (size_t)NTOK * DD;
    float* x    = (float*)d_ws;
    float* h    = x + BSD;
    float* q    = h + BSD;
    float* kbuf = q + BSD;
    float* vbuf = kbuf + BSD;
    unsigned short* h_bf   = (unsigned short*)(vbuf + BSD);       // MPAD*DD
    unsigned short* mlp_bf = h_bf + (size_t)MPAD * DD;            // MPAD*FF
    unsigned short* W1_bf  = mlp_bf + (size_t)MPAD * FF;          // FF*DD
    unsigned short* W2_bf  = W1_bf + (size_t)FF * DD;             // FF*DD
    unsigned short* We_bf  = W2_bf + (size_t)FF * DD;             // DD*DD
    unsigned short* P_bf   = mlp_bf;                              // alias (pre-loop only)

    // embed
    k_conv<<<576, 256, 0, stream>>>(W_embed, We_bf, DD * DD / 4);
    k_patchify<<<1024, 256, 0, stream>>>(image, P_bf);
    k_gemm_bf<0><<<dim3(6, 49), 256, 0, stream>>>(P_bf, We_bf, b_embed, x,
                                                  BB * NPATCH, DD, DD);
    k_posadd<<<1024, 256, 0, stream>>>(x, cls);

    for (int l = 0; l < LL; ++l) {
        const float* Wq_l = Wq + (size_t)l * HH * DHD * DHD;
        const float* Wk_l = Wk + (size_t)l * HH * DHD * DHD;
        const float* Wv_l = Wv + (size_t)l * HH * DHD * DHD;
        k_ln<0><<<NTOK, 256, 0, stream>>>(x, ln1g + l * DD, ln1b + l * DD, h, nullptr);
        k_qkv<<<(NTOK + 7) / 8, 256, 0, stream>>>(h, Wq_l, bq + l * DD, Wk_l, bk + l * DD,
                                                  Wv_l, bv + l * DD, q, kbuf, vbuf);
        k_attn2<<<dim3(13, HH, BB), 128, 0, stream>>>(q, kbuf, vbuf, x);
        k_ln<1><<<NTOK, 256, 0, stream>>>(x, ln2g + l * DD, ln2b + l * DD, nullptr, h_bf);
        k_conv<<<2304, 256, 0, stream>>>(W1 + (size_t)l * FF * DD, W1_bf, FF * DD / 4);
        k_conv<<<2304, 256, 0, stream>>>(W2 + (size_t)l * DD * FF, W2_bf, FF * DD / 4);
        k_gemm_bf<1><<<dim3(FF / 128, MPAD / 128), 256, 0, stream>>>(
            h_bf, W1_bf, b1 + (size_t)l * FF, mlp_bf, NTOK, FF, DD);
        k_gemm_bf<2><<<dim3(DD / 128, MPAD / 128), 256, 0, stream>>>(
            mlp_bf, W2_bf, b2 + (size_t)l * DD, x, NTOK, DD, FF);
    }

    k_head<<<dim3(4, BB), 256, 0, stream>>>(x, Wh, bh, out);
}

// Round 3
// 5727.661 us; speedup vs baseline: 4.7749x; 2.2342x over previous
//
#include <hip/hip_runtime.h>
#include <math.h>

// ---- problem constants ----
#define BB 32
#define SS 197
#define DD 768
#define HH 12
#define DHD 64
#define LL 12
#define FF 3072
#define NPATCH 196
#define NTOK (BB * SS)          // 6304
#define MPAD 6400               // NTOK padded to multiple of 128
#define LNEPS 1e-5f

typedef short bf8_t __attribute__((ext_vector_type(8)));
typedef float f4_t  __attribute__((ext_vector_type(4)));

__device__ __forceinline__ unsigned short f2bf(float x) {
    unsigned u = __float_as_uint(x);
    return (unsigned short)((u + 0x8000u) >> 16);
}
__device__ __forceinline__ float bf_lo(unsigned u) { return __uint_as_float(u << 16); }
__device__ __forceinline__ float bf_hi(unsigned u) { return __uint_as_float(u & 0xffff0000u); }

__device__ __forceinline__ void gl_lds16(const void* g, void* l) {
    __builtin_amdgcn_global_load_lds((const __attribute__((address_space(1))) unsigned int*)g,
                                     (__attribute__((address_space(3))) unsigned int*)l, 16, 0, 0);
}

// =====================================================================
// fp32 -> bf16 converter (weights)
// =====================================================================
__global__ __launch_bounds__(256) void k_conv(const float* __restrict__ a,
                                              unsigned short* __restrict__ o, int n4) {
    for (int i = blockIdx.x * 256 + threadIdx.x; i < n4; i += gridDim.x * 256) {
        float4 v = ((const float4*)a)[i];
        ushort4 r;
        r.x = f2bf(v.x); r.y = f2bf(v.y); r.z = f2bf(v.z); r.w = f2bf(v.w);
        ((ushort4*)o)[i] = r;
    }
}

// =====================================================================
// patchify: image [B,3,224,224] -> P_bf [B*196, 768] bf16, order (c,pi,pj)
// =====================================================================
__global__ __launch_bounds__(256) void k_patchify(const float* __restrict__ img,
                                                  unsigned short* __restrict__ P) {
    const int total = BB * NPATCH * DD;
    for (int idx = blockIdx.x * 256 + threadIdx.x; idx < total; idx += gridDim.x * 256) {
        int e = idx % DD;
        int rest = idx / DD;
        int p = rest % NPATCH;
        int b = rest / NPATCH;
        int c = e >> 8;
        int pi = (e >> 4) & 15;
        int pj = e & 15;
        int i = p / 14, j = p % 14;
        P[idx] = f2bf(img[(((size_t)b * 3 + c) * 224 + (i * 16 + pi)) * 224 + (j * 16 + pj)]);
    }
}

// =====================================================================
// bf16 MFMA GEMM (m97 structure): C[m,n] = A[m,k] * W[n,k]^T + bias
// EPI: 0 = embed (remap rows, f32 store), 1 = GELU -> bf16, 2 = res add f32
// =====================================================================
template <int EPI>
__global__ __launch_bounds__(256) void k_gemm_bf(const unsigned short* __restrict__ A,
                                                 const unsigned short* __restrict__ Bw,
                                                 const float* __restrict__ bias,
                                                 void* __restrict__ Cout,
                                                 int M, int N, int K) {
    __shared__ unsigned short As[128 * 32];
    __shared__ unsigned short Bs[128 * 32];
    const int tid = threadIdx.x;
    const int wave = tid >> 6, lane = tid & 63;
    const int m0 = blockIdx.y << 7, n0 = blockIdx.x << 7;

    const int r0 = tid >> 2, kp = (tid & 3) * 8;
    const unsigned short* gA0 = A + (size_t)(m0 + r0) * K + kp;
    const unsigned short* gA1 = A + (size_t)(m0 + 64 + r0) * K + kp;
    const unsigned short* gB0 = Bw + (size_t)(n0 + r0) * K + kp;
    const unsigned short* gB1 = Bw + (size_t)(n0 + 64 + r0) * K + kp;
    unsigned short* lA0 = &As[tid * 8];
    unsigned short* lA1 = &As[(tid + 256) * 8];
    unsigned short* lB0 = &Bs[tid * 8];
    unsigned short* lB1 = &Bs[(tid + 256) * 8];

    const int mh = (wave >> 1) << 6, nh = (wave & 1) << 6;
    const int lm = lane & 15, kq = lane >> 4;

    f4_t acc[4][4];
#pragma unroll
    for (int i = 0; i < 4; ++i)
#pragma unroll
        for (int j = 0; j < 4; ++j) acc[i][j] = (f4_t){0.f, 0.f, 0.f, 0.f};

    for (int k0 = 0; k0 < K; k0 += 32) {
        gl_lds16(gA0, lA0);
        gl_lds16(gA1, lA1);
        gl_lds16(gB0, lB0);
        gl_lds16(gB1, lB1);
        gA0 += 32; gA1 += 32; gB0 += 32; gB1 += 32;
        __syncthreads();
        bf8_t af[4], bfr[4];
#pragma unroll
        for (int mt = 0; mt < 4; ++mt)
            af[mt] = *(const bf8_t*)&As[(mh + mt * 16 + lm) * 32 + kq * 8];
#pragma unroll
        for (int nt = 0; nt < 4; ++nt)
            bfr[nt] = *(const bf8_t*)&Bs[(nh + nt * 16 + lm) * 32 + kq * 8];
#pragma unroll
        for (int mt = 0; mt < 4; ++mt)
#pragma unroll
            for (int nt = 0; nt < 4; ++nt)
                acc[mt][nt] = __builtin_amdgcn_mfma_f32_16x16x32_bf16(af[mt], bfr[nt],
                                                                      acc[mt][nt], 0, 0, 0);
        __syncthreads();
    }

    const int rbase = m0 + mh + kq * 4;
    const int cbase = n0 + nh + lm;
#pragma unroll
    for (int mt = 0; mt < 4; ++mt) {
#pragma unroll
        for (int nt = 0; nt < 4; ++nt) {
            const int col = cbase + nt * 16;
            const float bv = bias[col];
#pragma unroll
            for (int r = 0; r < 4; ++r) {
                const int row = rbase + mt * 16 + r;
                float val = acc[mt][nt][r] + bv;
                if (EPI == 0) {
                    size_t om = (size_t)(row / 196) * 197 + (row % 196) + 1;
                    ((float*)Cout)[om * DD + col] = val;
                } else if (EPI == 1) {
                    val = 0.5f * val * (1.f + erff(val * 0.7071067811865476f));
                    ((unsigned short*)Cout)[(size_t)row * N + col] = f2bf(val);
                } else {
                    if (row < M) ((float*)Cout)[(size_t)row * DD + col] += val;
                }
            }
        }
    }
}

// =====================================================================
// QKV via MFMA: block = (head, 128-token tile). A = h_bf[128,64(head)],
// B = [Wq;Wk;Wv](head) [192,64]. K=64 staged once, single barrier.
// LDS layout [khalf][row][32] keeps ds_read_b128 at 64B row stride.
// =====================================================================
__global__ __launch_bounds__(256) void k_qkv_mfma(const unsigned short* __restrict__ h,
                                                  const unsigned short* __restrict__ Wqb,
                                                  const unsigned short* __restrict__ Wkb,
                                                  const unsigned short* __restrict__ Wvb,
                                                  const float* __restrict__ bq,
                                                  const float* __restrict__ bk,
                                                  const float* __restrict__ bv,
                                                  unsigned short* __restrict__ qo,
                                                  unsigned short* __restrict__ ko,
                                                  unsigned short* __restrict__ vo) {
    __shared__ unsigned short As[2 * 128 * 32];       // [khalf][row][32]
    __shared__ unsigned short Bs[3 * 2 * 64 * 32];    // [mat][khalf][row][32]
    const int head = blockIdx.x;
    const int m0 = blockIdx.y << 7;
    const int tid = threadIdx.x;
    const int wave = tid >> 6, lane = tid & 63;
    const int lm = lane & 15, kq = lane >> 4;

    // ---- stage A: 1024 x 16B chunks ----
#pragma unroll
    for (int j = 0; j < 4; ++j) {
        int khalf = j >> 1;
        int rem = (j & 1) * 256 + tid;           // 0..511
        int row = rem >> 2, koff = (rem & 3) * 8;
        gl_lds16(h + (size_t)(m0 + row) * DD + head * 64 + khalf * 32 + koff,
                 &As[(j * 256 + tid) * 8]);
    }
    // ---- stage B: 1536 x 16B chunks ----
    const unsigned short* Wq_h = Wqb + head * 4096;
    const unsigned short* Wk_h = Wkb + head * 4096;
    const unsigned short* Wv_h = Wvb + head * 4096;
#pragma unroll
    for (int j = 0; j < 6; ++j) {
        const unsigned short* src = (j < 2) ? Wq_h : ((j < 4) ? Wk_h : Wv_h);
        int cm = (j & 1) * 256 + tid;            // 0..511 within mat
        int khalf = cm >> 8;
        int rem2 = cm & 255;
        int row = rem2 >> 2, koff = (rem2 & 3) * 8;
        gl_lds16(src + row * 64 + khalf * 32 + koff, &Bs[(j * 256 + tid) * 8]);
    }
    __syncthreads();

    f4_t acc[2][12];
#pragma unroll
    for (int i = 0; i < 2; ++i)
#pragma unroll
        for (int j = 0; j < 12; ++j) acc[i][j] = (f4_t){0.f, 0.f, 0.f, 0.f};

#pragma unroll
    for (int kh = 0; kh < 2; ++kh) {
        bf8_t af[2], bfr[12];
#pragma unroll
        for (int mt = 0; mt < 2; ++mt)
            af[mt] = *(const bf8_t*)&As[kh * 4096 + (wave * 32 + mt * 16 + lm) * 32 + kq * 8];
#pragma unroll
        for (int nt = 0; nt < 12; ++nt)
            bfr[nt] = *(const bf8_t*)&Bs[(nt >> 2) * 4096 + kh * 2048 +
                                         ((nt & 3) * 16 + lm) * 32 + kq * 8];
#pragma unroll
        for (int mt = 0; mt < 2; ++mt)
#pragma unroll
            for (int nt = 0; nt < 12; ++nt)
                acc[mt][nt] = __builtin_amdgcn_mfma_f32_16x16x32_bf16(af[mt], bfr[nt],
                                                                      acc[mt][nt], 0, 0, 0);
    }

    // epilogue: row = m0 + wave*32 + mt*16 + kq*4 + r, col192 = nt*16 + lm
    const int rbase = m0 + wave * 32 + kq * 4;
#pragma unroll
    for (int mt = 0; mt < 2; ++mt) {
#pragma unroll
        for (int nt = 0; nt < 12; ++nt) {
            const int col = nt * 16 + lm;
            const int e = col & 63;
            const float* bsrc = (nt < 4) ? bq : ((nt < 8) ? bk : bv);
            unsigned short* dst = (nt < 4) ? qo : ((nt < 8) ? ko : vo);
            const float bval = bsrc[head * 64 + e];
#pragma unroll
            for (int r = 0; r < 4; ++r) {
                const int row = rbase + mt * 16 + r;
                if (row < NTOK)
                    dst[(size_t)row * DD + head * 64 + e] = f2bf(acc[mt][nt][r] + bval);
            }
        }
    }
}

// =====================================================================
// pos-embed add (+cls for s==0)
// =====================================================================
__global__ __launch_bounds__(256) void k_posadd(float* __restrict__ x,
                                                const float* __restrict__ cls) {
    const int total = BB * SS * DD;
    const float LN1E4 = 9.210340371976184f;
    for (int idx = blockIdx.x * 256 + threadIdx.x; idx < total; idx += gridDim.x * 256) {
        int d = idx % DD;
        int s = (idx / DD) % SS;
        float ang = (float)s * __expf(-LN1E4 * (float)(2 * (d >> 1)) / 768.f);
        float pv = (d & 1) ? __cosf(ang) : __sinf(ang);
        if (s == 0) x[idx] = cls[d] + pv;
        else        x[idx] += pv;
    }
}

// =====================================================================
// LayerNorm: wave per row (4 rows/block), lane holds 12 elems, bf16 out
// =====================================================================
__global__ __launch_bounds__(256) void k_ln2(const float* __restrict__ x,
                                             const float* __restrict__ g,
                                             const float* __restrict__ bp,
                                             unsigned short* __restrict__ out) {
    const int row = blockIdx.x * 4 + (threadIdx.x >> 6);
    const int lane = threadIdx.x & 63;
    if (row >= NTOK) return;
    const float* xr = x + (size_t)row * DD + lane * 12;
    float4 a = ((const float4*)xr)[0];
    float4 b = ((const float4*)xr)[1];
    float4 c = ((const float4*)xr)[2];
    float s = a.x + a.y + a.z + a.w + b.x + b.y + b.z + b.w + c.x + c.y + c.z + c.w;
#pragma unroll
    for (int o = 32; o; o >>= 1) s += __shfl_xor(s, o);
    const float mean = s * (1.f / DD);
    float vr = 0.f, e0;
    e0 = a.x - mean; vr += e0 * e0; e0 = a.y - mean; vr += e0 * e0;
    e0 = a.z - mean; vr += e0 * e0; e0 = a.w - mean; vr += e0 * e0;
    e0 = b.x - mean; vr += e0 * e0; e0 = b.y - mean; vr += e0 * e0;
    e0 = b.z - mean; vr += e0 * e0; e0 = b.w - mean; vr += e0 * e0;
    e0 = c.x - mean; vr += e0 * e0; e0 = c.y - mean; vr += e0 * e0;
    e0 = c.z - mean; vr += e0 * e0; e0 = c.w - mean; vr += e0 * e0;
#pragma unroll
    for (int o = 32; o; o >>= 1) vr += __shfl_xor(vr, o);
    const float rstd = rsqrtf(vr * (1.f / DD) + LNEPS);

    const float4* g4 = (const float4*)(g + lane * 12);
    const float4* b4p = (const float4*)(bp + lane * 12);
    unsigned short* op = out + (size_t)row * DD + lane * 12;
    float4 gv, bv;
    ushort4 r;
    gv = g4[0]; bv = b4p[0];
    r.x = f2bf((a.x - mean) * rstd * gv.x + bv.x);
    r.y = f2bf((a.y - mean) * rstd * gv.y + bv.y);
    r.z = f2bf((a.z - mean) * rstd * gv.z + bv.z);
    r.w = f2bf((a.w - mean) * rstd * gv.w + bv.w);
    ((ushort4*)op)[0] = r;
    gv = g4[1]; bv = b4p[1];
    r.x = f2bf((b.x - mean) * rstd * gv.x + bv.x);
    r.y = f2bf((b.y - mean) * rstd * gv.y + bv.y);
    r.z = f2bf((b.z - mean) * rstd * gv.z + bv.z);
    r.w = f2bf((b.w - mean) * rstd * gv.w + bv.w);
    ((ushort4*)op)[1] = r;
    gv = g4[2]; bv = b4p[2];
    r.x = f2bf((c.x - mean) * rstd * gv.x + bv.x);
    r.y = f2bf((c.y - mean) * rstd * gv.y + bv.y);
    r.z = f2bf((c.z - mean) * rstd * gv.z + bv.z);
    r.w = f2bf((c.w - mean) * rstd * gv.w + bv.w);
    ((ushort4*)op)[2] = r;
}

// =====================================================================
// attention: block = (16 queries, head, b), 128 thr; bf16 q/k/v inputs
// =====================================================================
__global__ __launch_bounds__(128) void k_attn2(const unsigned short* __restrict__ qg,
                                               const unsigned short* __restrict__ kg,
                                               const unsigned short* __restrict__ vg,
                                               float* __restrict__ x) {
    const int qb = blockIdx.x, head = blockIdx.y, b = blockIdx.z;
    const int tid = threadIdx.x, wave = tid >> 6, lane = tid & 63;
    const size_t base = (size_t)b * SS * DD + (head << 6);

    __shared__ unsigned short Kt[64][200];
    __shared__ unsigned short Vs[SS][64];
    __shared__ float qs[2][64][8];
    __shared__ unsigned ps[2][50][20];

    for (int idx = tid; idx < SS * DHD; idx += 128) {
        int t = idx >> 6, e = idx & 63;
        Kt[e][t] = kg[base + (size_t)t * DD + e];
        Vs[t][e] = vg[base + (size_t)t * DD + e];
    }
    if (tid < 192) { int t = SS + tid / 64, e = tid % 64; Kt[e][t] = 0; }

    const int q0 = qb * 16 + wave * 8;
#pragma unroll
    for (int i = 0; i < 8; ++i) {
        int sr = q0 + i;
        qs[wave][lane][i] = (sr < SS) ? bf_lo((unsigned)qg[base + (size_t)sr * DD + lane]) : 0.f;
    }
    __syncthreads();

    float sc[8][4];
#pragma unroll
    for (int i = 0; i < 8; ++i)
#pragma unroll
        for (int j = 0; j < 4; ++j) sc[i][j] = 0.f;

    if (lane < 50) {
        const unsigned* K2 = (const unsigned*)Kt;
        for (int e = 0; e < 64; ++e) {
            f4_t qa = *(const f4_t*)&qs[wave][e][0];
            f4_t qb4 = *(const f4_t*)&qs[wave][e][4];
            uint2 kk = *(const uint2*)&K2[e * 100 + (lane << 1)];
            float k0 = bf_lo(kk.x), k1 = bf_hi(kk.x), k2 = bf_lo(kk.y), k3 = bf_hi(kk.y);
#pragma unroll
            for (int i = 0; i < 4; ++i) {
                sc[i][0] += qa[i] * k0; sc[i][1] += qa[i] * k1;
                sc[i][2] += qa[i] * k2; sc[i][3] += qa[i] * k3;
                sc[i + 4][0] += qb4[i] * k0; sc[i + 4][1] += qb4[i] * k1;
                sc[i + 4][2] += qb4[i] * k2; sc[i + 4][3] += qb4[i] * k3;
            }
        }
    }

    float inv[8];
#pragma unroll
    for (int i = 0; i < 8; ++i) {
        float s0 = sc[i][0] * 0.125f, s1 = sc[i][1] * 0.125f;
        float s2 = sc[i][2] * 0.125f, s3 = sc[i][3] * 0.125f;
        int t0 = lane << 2;
        if (t0 + 0 >= SS) s0 = -1e30f;
        if (t0 + 1 >= SS) s1 = -1e30f;
        if (t0 + 2 >= SS) s2 = -1e30f;
        if (t0 + 3 >= SS) s3 = -1e30f;
        float m = fmaxf(fmaxf(s0, s1), fmaxf(s2, s3));
#pragma unroll
        for (int o = 32; o; o >>= 1) m = fmaxf(m, __shfl_xor(m, o));
        float p0 = __expf(s0 - m), p1 = __expf(s1 - m);
        float p2 = __expf(s2 - m), p3 = __expf(s3 - m);
        float sm = p0 + p1 + p2 + p3;
#pragma unroll
        for (int o = 32; o; o >>= 1) sm += __shfl_xor(sm, o);
        inv[i] = 1.f / sm;
        sc[i][0] = p0; sc[i][1] = p1; sc[i][2] = p2; sc[i][3] = p3;
    }

    if (lane < 50) {
#pragma unroll
        for (int j = 0; j < 4; ++j)
#pragma unroll
            for (int i2 = 0; i2 < 4; ++i2) {
                unsigned pa = (__float_as_uint(sc[2 * i2][j]) + 0x8000u) >> 16;
                unsigned pb = (__float_as_uint(sc[2 * i2 + 1][j]) + 0x8000u) & 0xffff0000u;
                ps[wave][lane][j * 4 + i2] = pa | pb;
            }
    }
    __syncthreads();

    float out[8] = {0.f, 0.f, 0.f, 0.f, 0.f, 0.f, 0.f, 0.f};
    for (int t4 = 0; t4 < 49; ++t4) {
#pragma unroll
        for (int j = 0; j < 4; ++j) {
            float vv = bf_lo((unsigned)Vs[t4 * 4 + j][lane]);
            uint4 pp = *(const uint4*)&ps[wave][t4][j * 4];
            out[0] += bf_lo(pp.x) * vv; out[1] += bf_hi(pp.x) * vv;
            out[2] += bf_lo(pp.y) * vv; out[3] += bf_hi(pp.y) * vv;
            out[4] += bf_lo(pp.z) * vv; out[5] += bf_hi(pp.z) * vv;
            out[6] += bf_lo(pp.w) * vv; out[7] += bf_hi(pp.w) * vv;
        }
    }
    {
        float vv = bf_lo((unsigned)Vs[196][lane]);
        uint4 pp = *(const uint4*)&ps[wave][49][0];
        out[0] += bf_lo(pp.x) * vv; out[1] += bf_hi(pp.x) * vv;
        out[2] += bf_lo(pp.y) * vv; out[3] += bf_hi(pp.y) * vv;
        out[4] += bf_lo(pp.z) * vv; out[5] += bf_hi(pp.z) * vv;
        out[6] += bf_lo(pp.w) * vv; out[7] += bf_hi(pp.w) * vv;
    }

#pragma unroll
    for (int i = 0; i < 8; ++i) {
        int sr = q0 + i;
        if (sr < SS) x[base + (size_t)sr * DD + lane] += out[i] * inv[i];
    }
}

// =====================================================================
// classifier head (fp32)
// =====================================================================
__global__ __launch_bounds__(256) void k_head(const float* __restrict__ x,
                                              const float* __restrict__ Wh,
                                              const float* __restrict__ bh,
                                              float* __restrict__ out) {
    const int b = blockIdx.y;
    const int c = blockIdx.x * 256 + threadIdx.x;
    __shared__ __align__(16) float xs[DD];
    const float* xr = x + (size_t)b * SS * DD;
    for (int d = threadIdx.x; d < DD; d += 256) xs[d] = xr[d];
    __syncthreads();
    if (c < 1000) {
        const float4* w4 = (const float4*)(Wh + (size_t)c * DD);
        float acc = 0.f;
#pragma unroll 4
        for (int d4 = 0; d4 < DD / 4; ++d4) {
            float4 w = w4[d4];
            const float4 xv = *(const float4*)&xs[d4 << 2];
            acc += xv.x * w.x + xv.y * w.y + xv.z * w.z + xv.w * w.w;
        }
        out[(size_t)b * 1000 + c] = acc + bh[c];
    }
}

// =====================================================================
extern "C" void kernel_launch(void* const* d_in, const int* in_sizes, int n_in,
                              void* d_out, int out_size, void* d_ws, size_t ws_size,
                              hipStream_t stream) {
    const float* image   = (const float*)d_in[0];
    const float* W_embed = (const float*)d_in[1];
    const float* b_embed = (const float*)d_in[2];
    const float* cls     = (const float*)d_in[3];
    const float* Wq      = (const float*)d_in[4];
    const float* bq      = (const float*)d_in[5];
    const float* Wk      = (const float*)d_in[6];
    const float* bk      = (const float*)d_in[7];
    const float* Wv      = (const float*)d_in[8];
    const float* bv      = (const float*)d_in[9];
    const float* ln1g    = (const float*)d_in[10];
    const float* ln1b    = (const float*)d_in[11];
    const float* ln2g    = (const float*)d_in[12];
    const float* ln2b    = (const float*)d_in[13];
    const float* W1      = (const float*)d_in[14];
    const float* b1      = (const float*)d_in[15];
    const float* W2      = (const float*)d_in[16];
    const float* b2      = (const float*)d_in[17];
    const float* Wh      = (const float*)d_in[18];
    const float* bh      = (const float*)d_in[19];
    float* out = (float*)d_out;

    float* x = (float*)d_ws;
    unsigned short* h_bf   = (unsigned short*)(x + (size_t)NTOK * DD);
    unsigned short* q_bf   = h_bf + (size_t)MPAD * DD;
    unsigned short* k_bf   = q_bf + (size_t)MPAD * DD;
    unsigned short* v_bf   = k_bf + (size_t)MPAD * DD;
    unsigned short* mlp_bf = v_bf + (size_t)MPAD * DD;            // MPAD*FF
    unsigned short* W1_bf  = mlp_bf + (size_t)MPAD * FF;
    unsigned short* W2_bf  = W1_bf + (size_t)FF * DD;
    unsigned short* We_bf  = W2_bf + (size_t)FF * DD;
    unsigned short* Wq_bf  = We_bf + (size_t)DD * DD;             // L*H*64*64
    unsigned short* Wk_bf  = Wq_bf + (size_t)LL * HH * DHD * DHD;
    unsigned short* Wv_bf  = Wk_bf + (size_t)LL * HH * DHD * DHD;
    unsigned short* P_bf   = mlp_bf;                              // alias pre-loop

    const int QKVW = LL * HH * DHD * DHD;                         // 589824

    // one-time weight conversions
    k_conv<<<576, 256, 0, stream>>>(W_embed, We_bf, DD * DD / 4);
    k_conv<<<576, 256, 0, stream>>>(Wq, Wq_bf, QKVW / 4);
    k_conv<<<576, 256, 0, stream>>>(Wk, Wk_bf, QKVW / 4);
    k_conv<<<576, 256, 0, stream>>>(Wv, Wv_bf, QKVW / 4);

    // embed
    k_patchify<<<1024, 256, 0, stream>>>(image, P_bf);
    k_gemm_bf<0><<<dim3(6, 49), 256, 0, stream>>>(P_bf, We_bf, b_embed, x,
                                                  BB * NPATCH, DD, DD);
    k_posadd<<<1024, 256, 0, stream>>>(x, cls);

    for (int l = 0; l < LL; ++l) {
        k_ln2<<<(NTOK + 3) / 4, 256, 0, stream>>>(x, ln1g + l * DD, ln1b + l * DD, h_bf);
        k_qkv_mfma<<<dim3(HH, MPAD / 128), 256, 0, stream>>>(
            h_bf, Wq_bf + (size_t)l * HH * 4096, Wk_bf + (size_t)l * HH * 4096,
            Wv_bf + (size_t)l * HH * 4096, bq + l * DD, bk + l * DD, bv + l * DD,
            q_bf, k_bf, v_bf);
        k_attn2<<<dim3(13, HH, BB), 128, 0, stream>>>(q_bf, k_bf, v_bf, x);
        k_ln2<<<(NTOK + 3) / 4, 256, 0, stream>>>(x, ln2g + l * DD, ln2b + l * DD, h_bf);
        k_conv<<<2304, 256, 0, stream>>>(W1 + (size_t)l * FF * DD, W1_bf, FF * DD / 4);
        k_conv<<<2304, 256, 0, stream>>>(W2 + (size_t)l * DD * FF, W2_bf, FF * DD / 4);
        k_gemm_bf<1><<<dim3(FF / 128, MPAD / 128), 256, 0, stream>>>(
            h_bf, W1_bf, b1 + (size_t)l * FF, mlp_bf, NTOK, FF, DD);
        k_gemm_bf<2><<<dim3(DD / 128, MPAD / 128), 256, 0, stream>>>(
            mlp_bf, W2_bf, b2 + (size_t)l * DD, x, NTOK, DD, FF);
    }

    k_head<<<dim3(4, BB), 256, 0, stream>>>(x, Wh, bh, out);
}

// Round 4
// 3092.578 us; speedup vs baseline: 8.8435x; 1.8521x over previous
//
#include <hip/hip_runtime.h>
#include <math.h>

// ---- problem constants ----
#define BB 32
#define SS 197
#define DD 768
#define HH 12
#define DHD 64
#define LL 12
#define FF 3072
#define NPATCH 196
#define NTOK (BB * SS)          // 6304
#define MPAD 6400               // NTOK padded to multiple of 128
#define LNEPS 1e-5f

typedef short bf8_t __attribute__((ext_vector_type(8)));
typedef float f4_t  __attribute__((ext_vector_type(4)));
typedef unsigned short u16x8 __attribute__((ext_vector_type(8)));

__device__ __forceinline__ unsigned short f2bf(float x) {
    unsigned u = __float_as_uint(x);
    return (unsigned short)((u + 0x8000u) >> 16);
}
__device__ __forceinline__ float bf_lo(unsigned u) { return __uint_as_float(u << 16); }

__device__ __forceinline__ void gl_lds16(const void* g, void* l) {
    __builtin_amdgcn_global_load_lds((const __attribute__((address_space(1))) unsigned int*)g,
                                     (__attribute__((address_space(3))) unsigned int*)l, 16, 0, 0);
}

// =====================================================================
// fp32 -> bf16 converter (weights)
// =====================================================================
__global__ __launch_bounds__(256) void k_conv(const float* __restrict__ a,
                                              unsigned short* __restrict__ o, int n4) {
    for (int i = blockIdx.x * 256 + threadIdx.x; i < n4; i += gridDim.x * 256) {
        float4 v = ((const float4*)a)[i];
        ushort4 r;
        r.x = f2bf(v.x); r.y = f2bf(v.y); r.z = f2bf(v.z); r.w = f2bf(v.w);
        ((ushort4*)o)[i] = r;
    }
}

// =====================================================================
// patchify: image [B,3,224,224] -> P_bf [B*196, 768] bf16, order (c,pi,pj)
// =====================================================================
__global__ __launch_bounds__(256) void k_patchify(const float* __restrict__ img,
                                                  unsigned short* __restrict__ P) {
    const int total = BB * NPATCH * DD;
    for (int idx = blockIdx.x * 256 + threadIdx.x; idx < total; idx += gridDim.x * 256) {
        int e = idx % DD;
        int rest = idx / DD;
        int p = rest % NPATCH;
        int b = rest / NPATCH;
        int c = e >> 8;
        int pi = (e >> 4) & 15;
        int pj = e & 15;
        int i = p / 14, j = p % 14;
        P[idx] = f2bf(img[(((size_t)b * 3 + c) * 224 + (i * 16 + pi)) * 224 + (j * 16 + pj)]);
    }
}

// =====================================================================
// bf16 MFMA GEMM (m97 structure): C[m,n] = A[m,k] * W[n,k]^T + bias
// EPI: 0 = embed (remap rows, f32 store), 1 = GELU -> bf16, 2 = res add f32
// =====================================================================
template <int EPI>
__global__ __launch_bounds__(256) void k_gemm_bf(const unsigned short* __restrict__ A,
                                                 const unsigned short* __restrict__ Bw,
                                                 const float* __restrict__ bias,
                                                 void* __restrict__ Cout,
                                                 int M, int N, int K) {
    __shared__ unsigned short As[128 * 32];
    __shared__ unsigned short Bs[128 * 32];
    const int tid = threadIdx.x;
    const int wave = tid >> 6, lane = tid & 63;
    const int m0 = blockIdx.y << 7, n0 = blockIdx.x << 7;

    const int r0 = tid >> 2, kp = (tid & 3) * 8;
    const unsigned short* gA0 = A + (size_t)(m0 + r0) * K + kp;
    const unsigned short* gA1 = A + (size_t)(m0 + 64 + r0) * K + kp;
    const unsigned short* gB0 = Bw + (size_t)(n0 + r0) * K + kp;
    const unsigned short* gB1 = Bw + (size_t)(n0 + 64 + r0) * K + kp;
    unsigned short* lA0 = &As[tid * 8];
    unsigned short* lA1 = &As[(tid + 256) * 8];
    unsigned short* lB0 = &Bs[tid * 8];
    unsigned short* lB1 = &Bs[(tid + 256) * 8];

    const int mh = (wave >> 1) << 6, nh = (wave & 1) << 6;
    const int lm = lane & 15, kq = lane >> 4;

    f4_t acc[4][4];
#pragma unroll
    for (int i = 0; i < 4; ++i)
#pragma unroll
        for (int j = 0; j < 4; ++j) acc[i][j] = (f4_t){0.f, 0.f, 0.f, 0.f};

    for (int k0 = 0; k0 < K; k0 += 32) {
        gl_lds16(gA0, lA0);
        gl_lds16(gA1, lA1);
        gl_lds16(gB0, lB0);
        gl_lds16(gB1, lB1);
        gA0 += 32; gA1 += 32; gB0 += 32; gB1 += 32;
        __syncthreads();
        bf8_t af[4], bfr[4];
#pragma unroll
        for (int mt = 0; mt < 4; ++mt)
            af[mt] = *(const bf8_t*)&As[(mh + mt * 16 + lm) * 32 + kq * 8];
#pragma unroll
        for (int nt = 0; nt < 4; ++nt)
            bfr[nt] = *(const bf8_t*)&Bs[(nh + nt * 16 + lm) * 32 + kq * 8];
#pragma unroll
        for (int mt = 0; mt < 4; ++mt)
#pragma unroll
            for (int nt = 0; nt < 4; ++nt)
                acc[mt][nt] = __builtin_amdgcn_mfma_f32_16x16x32_bf16(af[mt], bfr[nt],
                                                                      acc[mt][nt], 0, 0, 0);
        __syncthreads();
    }

    const int rbase = m0 + mh + kq * 4;
    const int cbase = n0 + nh + lm;
#pragma unroll
    for (int mt = 0; mt < 4; ++mt) {
#pragma unroll
        for (int nt = 0; nt < 4; ++nt) {
            const int col = cbase + nt * 16;
            const float bv = bias[col];
#pragma unroll
            for (int r = 0; r < 4; ++r) {
                const int row = rbase + mt * 16 + r;
                float val = acc[mt][nt][r] + bv;
                if (EPI == 0) {
                    size_t om = (size_t)(row / 196) * 197 + (row % 196) + 1;
                    ((float*)Cout)[om * DD + col] = val;
                } else if (EPI == 1) {
                    val = 0.5f * val * (1.f + erff(val * 0.7071067811865476f));
                    ((unsigned short*)Cout)[(size_t)row * N + col] = f2bf(val);
                } else {
                    if (row < M) ((float*)Cout)[(size_t)row * DD + col] += val;
                }
            }
        }
    }
}

// =====================================================================
// QKV via MFMA: block = (head, 128-token tile). Single-barrier K=64.
// =====================================================================
__global__ __launch_bounds__(256) void k_qkv_mfma(const unsigned short* __restrict__ h,
                                                  const unsigned short* __restrict__ Wqb,
                                                  const unsigned short* __restrict__ Wkb,
                                                  const unsigned short* __restrict__ Wvb,
                                                  const float* __restrict__ bq,
                                                  const float* __restrict__ bk,
                                                  const float* __restrict__ bv,
                                                  unsigned short* __restrict__ qo,
                                                  unsigned short* __restrict__ ko,
                                                  unsigned short* __restrict__ vo) {
    __shared__ unsigned short As[2 * 128 * 32];       // [khalf][row][32]
    __shared__ unsigned short Bs[3 * 2 * 64 * 32];    // [mat][khalf][row][32]
    const int head = blockIdx.x;
    const int m0 = blockIdx.y << 7;
    const int tid = threadIdx.x;
    const int wave = tid >> 6, lane = tid & 63;
    const int lm = lane & 15, kq = lane >> 4;

#pragma unroll
    for (int j = 0; j < 4; ++j) {
        int khalf = j >> 1;
        int rem = (j & 1) * 256 + tid;           // 0..511
        int row = rem >> 2, koff = (rem & 3) * 8;
        gl_lds16(h + (size_t)(m0 + row) * DD + head * 64 + khalf * 32 + koff,
                 &As[(j * 256 + tid) * 8]);
    }
    const unsigned short* Wq_h = Wqb + head * 4096;
    const unsigned short* Wk_h = Wkb + head * 4096;
    const unsigned short* Wv_h = Wvb + head * 4096;
#pragma unroll
    for (int j = 0; j < 6; ++j) {
        const unsigned short* src = (j < 2) ? Wq_h : ((j < 4) ? Wk_h : Wv_h);
        int cm = (j & 1) * 256 + tid;            // 0..511 within mat
        int khalf = cm >> 8;
        int rem2 = cm & 255;
        int row = rem2 >> 2, koff = (rem2 & 3) * 8;
        gl_lds16(src + row * 64 + khalf * 32 + koff, &Bs[(j * 256 + tid) * 8]);
    }
    __syncthreads();

    f4_t acc[2][12];
#pragma unroll
    for (int i = 0; i < 2; ++i)
#pragma unroll
        for (int j = 0; j < 12; ++j) acc[i][j] = (f4_t){0.f, 0.f, 0.f, 0.f};

#pragma unroll
    for (int kh = 0; kh < 2; ++kh) {
        bf8_t af[2], bfr[12];
#pragma unroll
        for (int mt = 0; mt < 2; ++mt)
            af[mt] = *(const bf8_t*)&As[kh * 4096 + (wave * 32 + mt * 16 + lm) * 32 + kq * 8];
#pragma unroll
        for (int nt = 0; nt < 12; ++nt)
            bfr[nt] = *(const bf8_t*)&Bs[(nt >> 2) * 4096 + kh * 2048 +
                                         ((nt & 3) * 16 + lm) * 32 + kq * 8];
#pragma unroll
        for (int mt = 0; mt < 2; ++mt)
#pragma unroll
            for (int nt = 0; nt < 12; ++nt)
                acc[mt][nt] = __builtin_amdgcn_mfma_f32_16x16x32_bf16(af[mt], bfr[nt],
                                                                      acc[mt][nt], 0, 0, 0);
    }

    const int rbase = m0 + wave * 32 + kq * 4;
#pragma unroll
    for (int mt = 0; mt < 2; ++mt) {
#pragma unroll
        for (int nt = 0; nt < 12; ++nt) {
            const int col = nt * 16 + lm;
            const int e = col & 63;
            const float* bsrc = (nt < 4) ? bq : ((nt < 8) ? bk : bv);
            unsigned short* dst = (nt < 4) ? qo : ((nt < 8) ? ko : vo);
            const float bval = bsrc[head * 64 + e];
#pragma unroll
            for (int r = 0; r < 4; ++r) {
                const int row = rbase + mt * 16 + r;
                if (row < NTOK)
                    dst[(size_t)row * DD + head * 64 + e] = f2bf(acc[mt][nt][r] + bval);
            }
        }
    }
}

// =====================================================================
// pos-embed add (+cls for s==0)
// =====================================================================
__global__ __launch_bounds__(256) void k_posadd(float* __restrict__ x,
                                                const float* __restrict__ cls) {
    const int total = BB * SS * DD;
    const float LN1E4 = 9.210340371976184f;
    for (int idx = blockIdx.x * 256 + threadIdx.x; idx < total; idx += gridDim.x * 256) {
        int d = idx % DD;
        int s = (idx / DD) % SS;
        float ang = (float)s * __expf(-LN1E4 * (float)(2 * (d >> 1)) / 768.f);
        float pv = (d & 1) ? __cosf(ang) : __sinf(ang);
        if (s == 0) x[idx] = cls[d] + pv;
        else        x[idx] += pv;
    }
}

// =====================================================================
// LayerNorm: wave per row (4 rows/block), lane holds 12 elems, bf16 out
// =====================================================================
__global__ __launch_bounds__(256) void k_ln2(const float* __restrict__ x,
                                             const float* __restrict__ g,
                                             const float* __restrict__ bp,
                                             unsigned short* __restrict__ out) {
    const int row = blockIdx.x * 4 + (threadIdx.x >> 6);
    const int lane = threadIdx.x & 63;
    if (row >= NTOK) return;
    const float* xr = x + (size_t)row * DD + lane * 12;
    float4 a = ((const float4*)xr)[0];
    float4 b = ((const float4*)xr)[1];
    float4 c = ((const float4*)xr)[2];
    float s = a.x + a.y + a.z + a.w + b.x + b.y + b.z + b.w + c.x + c.y + c.z + c.w;
#pragma unroll
    for (int o = 32; o; o >>= 1) s += __shfl_xor(s, o);
    const float mean = s * (1.f / DD);
    float vr = 0.f, e0;
    e0 = a.x - mean; vr += e0 * e0; e0 = a.y - mean; vr += e0 * e0;
    e0 = a.z - mean; vr += e0 * e0; e0 = a.w - mean; vr += e0 * e0;
    e0 = b.x - mean; vr += e0 * e0; e0 = b.y - mean; vr += e0 * e0;
    e0 = b.z - mean; vr += e0 * e0; e0 = b.w - mean; vr += e0 * e0;
    e0 = c.x - mean; vr += e0 * e0; e0 = c.y - mean; vr += e0 * e0;
    e0 = c.z - mean; vr += e0 * e0; e0 = c.w - mean; vr += e0 * e0;
#pragma unroll
    for (int o = 32; o; o >>= 1) vr += __shfl_xor(vr, o);
    const float rstd = rsqrtf(vr * (1.f / DD) + LNEPS);

    const float4* g4 = (const float4*)(g + lane * 12);
    const float4* b4p = (const float4*)(bp + lane * 12);
    unsigned short* op = out + (size_t)row * DD + lane * 12;
    float4 gv, bv;
    ushort4 r;
    gv = g4[0]; bv = b4p[0];
    r.x = f2bf((a.x - mean) * rstd * gv.x + bv.x);
    r.y = f2bf((a.y - mean) * rstd * gv.y + bv.y);
    r.z = f2bf((a.z - mean) * rstd * gv.z + bv.z);
    r.w = f2bf((a.w - mean) * rstd * gv.w + bv.w);
    ((ushort4*)op)[0] = r;
    gv = g4[1]; bv = b4p[1];
    r.x = f2bf((b.x - mean) * rstd * gv.x + bv.x);
    r.y = f2bf((b.y - mean) * rstd * gv.y + bv.y);
    r.z = f2bf((b.z - mean) * rstd * gv.z + bv.z);
    r.w = f2bf((b.w - mean) * rstd * gv.w + bv.w);
    ((ushort4*)op)[1] = r;
    gv = g4[2]; bv = b4p[2];
    r.x = f2bf((c.x - mean) * rstd * gv.x + bv.x);
    r.y = f2bf((c.y - mean) * rstd * gv.y + bv.y);
    r.z = f2bf((c.z - mean) * rstd * gv.z + bv.z);
    r.w = f2bf((c.w - mean) * rstd * gv.w + bv.w);
    ((ushort4*)op)[2] = r;
}

// =====================================================================
// attention v3 (MFMA): block = (64-query tile, head, b), 256 thr = 4 waves.
// S^T = K.Q^T via mfma (A=K rows, B=Q rows) -> softmax over t in-register
// (local + 2 shuffles) -> P round-trip LDS into A-layout -> O = P.V via
// mfma with V staged transposed (Vt[e][t], stride 232: frag reads clean).
// LDS: region0 = union{ K[2][224][32], P[4][16][232] }, region1 = Vt[64][232].
// =====================================================================
__global__ __launch_bounds__(256) void k_attn3(const unsigned short* __restrict__ qg,
                                               const unsigned short* __restrict__ kg,
                                               const unsigned short* __restrict__ vg,
                                               float* __restrict__ x) {
    const int qt = blockIdx.x, head = blockIdx.y, b = blockIdx.z;
    const int tid = threadIdx.x, wv = tid >> 6, lane = tid & 63;
    const int lm = lane & 15, kq = lane >> 4;

    __shared__ __align__(16) unsigned short lds[29696];   // 59392 B
    unsigned short* Kl = lds;            // [kh][224][32] = 14336 sh
    unsigned short* Pl = lds;            // [4][16][232]  = 14848 sh (aliases K)
    unsigned short* Vt = lds + 14848;    // [64][232]     = 14848 sh

    const size_t tokbase = (size_t)b * SS;
    const unsigned short* kb = kg + tokbase * DD + head * 64;
    const unsigned short* vb = vg + tokbase * DD + head * 64;
    const unsigned short* qb = qg + tokbase * DD + head * 64;

    // ---- stage K: [kh][t(224)][32], 1792 x 16B chunks via global_load_lds ----
#pragma unroll
    for (int it = 0; it < 7; ++it) {
        int c = it * 256 + tid;
        int kh = c / 896, rem = c - kh * 896;
        int t = rem >> 2, cc = rem & 3;
        gl_lds16(kb + (size_t)t * DD + kh * 32 + cc * 8, (char*)lds + c * 16);
    }
    // ---- stage V transposed: Vt[e][t], t padded 224 (197.. zeroed) ----
#pragma unroll
    for (int it = 0; it < 7; ++it) {
        int idx = it * 256 + tid;
        int t = idx >> 3, eg = idx & 7;
        if (t < SS) {
            u16x8 v8 = *(const u16x8*)(vb + (size_t)t * DD + eg * 8);
#pragma unroll
            for (int j = 0; j < 8; ++j) Vt[(eg * 8 + j) * 232 + t] = v8[j];
        } else {
#pragma unroll
            for (int j = 0; j < 8; ++j) Vt[(eg * 8 + j) * 232 + t] = 0;
        }
    }

    // ---- Q fragments (B-operand) straight from global ----
    const int qrow = qt * 64 + wv * 16 + lm;
    bf8_t qf0 = *(const bf8_t*)(qb + (size_t)qrow * DD + kq * 8);
    bf8_t qf1 = *(const bf8_t*)(qb + (size_t)qrow * DD + 32 + kq * 8);

    __syncthreads();

    // ---- S^T: D[t-tile][q16] ; 13 t-tiles x 2 kh ----
    f4_t sacc[13];
#pragma unroll
    for (int tt = 0; tt < 13; ++tt) sacc[tt] = (f4_t){0.f, 0.f, 0.f, 0.f};
#pragma unroll
    for (int tt = 0; tt < 13; ++tt) {
        bf8_t a0 = *(const bf8_t*)&Kl[(tt * 16 + lm) * 32 + kq * 8];
        bf8_t a1 = *(const bf8_t*)&Kl[7168 + (tt * 16 + lm) * 32 + kq * 8];
        sacc[tt] = __builtin_amdgcn_mfma_f32_16x16x32_bf16(a0, qf0, sacc[tt], 0, 0, 0);
        sacc[tt] = __builtin_amdgcn_mfma_f32_16x16x32_bf16(a1, qf1, sacc[tt], 0, 0, 0);
    }

    // ---- softmax over t for q = lm (local over 52 vals + xor16 + xor32) ----
    float mx = -1e30f;
#pragma unroll
    for (int tt = 0; tt < 13; ++tt)
#pragma unroll
        for (int r = 0; r < 4; ++r) {
            float s = sacc[tt][r] * 0.125f;
            if (tt == 12 && (kq * 4 + r) >= 5) s = -1e30f;   // t = 192+kq*4+r >= 197
            sacc[tt][r] = s;
            mx = fmaxf(mx, s);
        }
    mx = fmaxf(mx, __shfl_xor(mx, 16));
    mx = fmaxf(mx, __shfl_xor(mx, 32));
    float sum = 0.f;
#pragma unroll
    for (int tt = 0; tt < 13; ++tt)
#pragma unroll
        for (int r = 0; r < 4; ++r) {
            float p = __expf(sacc[tt][r] - mx);
            sacc[tt][r] = p;
            sum += p;
        }
    sum += __shfl_xor(sum, 16);
    sum += __shfl_xor(sum, 32);
    const float inv = 1.f / sum;

    __syncthreads();   // all waves done reading K -> safe to overwrite with P

    // ---- write P (A-layout rows [q][t], per-wave region) ----
    unsigned short* Pw = Pl + wv * 3712;
#pragma unroll
    for (int tt = 0; tt < 13; ++tt)
#pragma unroll
        for (int r = 0; r < 4; ++r)
            Pw[lm * 232 + tt * 16 + kq * 4 + r] = f2bf(sacc[tt][r]);
    // zero pad t = 208..223
    *(short4*)&Pw[lm * 232 + 208 + kq * 4] = make_short4(0, 0, 0, 0);

    // ---- PV: O[q][e] ; 7 k-chunks x 4 e-tiles (same-wave P, no barrier) ----
    f4_t oacc[4];
#pragma unroll
    for (int et = 0; et < 4; ++et) oacc[et] = (f4_t){0.f, 0.f, 0.f, 0.f};
#pragma unroll
    for (int kc = 0; kc < 7; ++kc) {
        bf8_t pa = *(const bf8_t*)&Pw[lm * 232 + kc * 32 + kq * 8];
#pragma unroll
        for (int et = 0; et < 4; ++et) {
            bf8_t vv = *(const bf8_t*)&Vt[(et * 16 + lm) * 232 + kc * 32 + kq * 8];
            oacc[et] = __builtin_amdgcn_mfma_f32_16x16x32_bf16(pa, vv, oacc[et], 0, 0, 0);
        }
    }

    // ---- 1/sum redistribution (softmax layout q=lm -> C layout q=kq*4+r) ----
    float invq[4];
#pragma unroll
    for (int r = 0; r < 4; ++r) invq[r] = __shfl(inv, kq * 4 + r);

    // ---- residual add into x ----
    float* xp = x + tokbase * DD + head * 64;
#pragma unroll
    for (int r = 0; r < 4; ++r) {
        const int qgr = qt * 64 + wv * 16 + kq * 4 + r;
        if (qgr < SS) {
#pragma unroll
            for (int et = 0; et < 4; ++et)
                xp[(size_t)qgr * DD + et * 16 + lm] += oacc[et][r] * invq[r];
        }
    }
}

// =====================================================================
// classifier head (fp32)
// =====================================================================
__global__ __launch_bounds__(256) void k_head(const float* __restrict__ x,
                                              const float* __restrict__ Wh,
                                              const float* __restrict__ bh,
                                              float* __restrict__ out) {
    const int b = blockIdx.y;
    const int c = blockIdx.x * 256 + threadIdx.x;
    __shared__ __align__(16) float xs[DD];
    const float* xr = x + (size_t)b * SS * DD;
    for (int d = threadIdx.x; d < DD; d += 256) xs[d] = xr[d];
    __syncthreads();
    if (c < 1000) {
        const float4* w4 = (const float4*)(Wh + (size_t)c * DD);
        float acc = 0.f;
#pragma unroll 4
        for (int d4 = 0; d4 < DD / 4; ++d4) {
            float4 w = w4[d4];
            const float4 xv = *(const float4*)&xs[d4 << 2];
            acc += xv.x * w.x + xv.y * w.y + xv.z * w.z + xv.w * w.w;
        }
        out[(size_t)b * 1000 + c] = acc + bh[c];
    }
}

// =====================================================================
extern "C" void kernel_launch(void* const* d_in, const int* in_sizes, int n_in,
                              void* d_out, int out_size, void* d_ws, size_t ws_size,
                              hipStream_t stream) {
    const float* image   = (const float*)d_in[0];
    const float* W_embed = (const float*)d_in[1];
    const float* b_embed = (const float*)d_in[2];
    const float* cls     = (const float*)d_in[3];
    const float* Wq      = (const float*)d_in[4];
    const float* bq      = (const float*)d_in[5];
    const float* Wk      = (const float*)d_in[6];
    const float* bk      = (const float*)d_in[7];
    const float* Wv      = (const float*)d_in[8];
    const float* bv      = (const float*)d_in[9];
    const float* ln1g    = (const float*)d_in[10];
    const float* ln1b    = (const float*)d_in[11];
    const float* ln2g    = (const float*)d_in[12];
    const float* ln2b    = (const float*)d_in[13];
    const float* W1      = (const float*)d_in[14];
    const float* b1      = (const float*)d_in[15];
    const float* W2      = (const float*)d_in[16];
    const float* b2      = (const float*)d_in[17];
    const float* Wh      = (const float*)d_in[18];
    const float* bh      = (const float*)d_in[19];
    float* out = (float*)d_out;

    float* x = (float*)d_ws;
    unsigned short* h_bf   = (unsigned short*)(x + (size_t)NTOK * DD);
    unsigned short* q_bf   = h_bf + (size_t)MPAD * DD;
    unsigned short* k_bf   = q_bf + (size_t)MPAD * DD;
    unsigned short* v_bf   = k_bf + (size_t)MPAD * DD;
    unsigned short* mlp_bf = v_bf + (size_t)MPAD * DD;            // MPAD*FF
    unsigned short* W1_bf  = mlp_bf + (size_t)MPAD * FF;
    unsigned short* W2_bf  = W1_bf + (size_t)FF * DD;
    unsigned short* We_bf  = W2_bf + (size_t)FF * DD;
    unsigned short* Wq_bf  = We_bf + (size_t)DD * DD;             // L*H*64*64
    unsigned short* Wk_bf  = Wq_bf + (size_t)LL * HH * DHD * DHD;
    unsigned short* Wv_bf  = Wk_bf + (size_t)LL * HH * DHD * DHD;
    unsigned short* P_bf   = mlp_bf;                              // alias pre-loop

    const int QKVW = LL * HH * DHD * DHD;                         // 589824

    // one-time weight conversions
    k_conv<<<576, 256, 0, stream>>>(W_embed, We_bf, DD * DD / 4);
    k_conv<<<576, 256, 0, stream>>>(Wq, Wq_bf, QKVW / 4);
    k_conv<<<576, 256, 0, stream>>>(Wk, Wk_bf, QKVW / 4);
    k_conv<<<576, 256, 0, stream>>>(Wv, Wv_bf, QKVW / 4);

    // embed
    k_patchify<<<1024, 256, 0, stream>>>(image, P_bf);
    k_gemm_bf<0><<<dim3(6, 49), 256, 0, stream>>>(P_bf, We_bf, b_embed, x,
                                                  BB * NPATCH, DD, DD);
    k_posadd<<<1024, 256, 0, stream>>>(x, cls);

    for (int l = 0; l < LL; ++l) {
        k_ln2<<<(NTOK + 3) / 4, 256, 0, stream>>>(x, ln1g + l * DD, ln1b + l * DD, h_bf);
        k_qkv_mfma<<<dim3(HH, MPAD / 128), 256, 0, stream>>>(
            h_bf, Wq_bf + (size_t)l * HH * 4096, Wk_bf + (size_t)l * HH * 4096,
            Wv_bf + (size_t)l * HH * 4096, bq + l * DD, bk + l * DD, bv + l * DD,
            q_bf, k_bf, v_bf);
        k_attn3<<<dim3(4, HH, BB), 256, 0, stream>>>(q_bf, k_bf, v_bf, x);
        k_ln2<<<(NTOK + 3) / 4, 256, 0, stream>>>(x, ln2g + l * DD, ln2b + l * DD, h_bf);
        k_conv<<<2304, 256, 0, stream>>>(W1 + (size_t)l * FF * DD, W1_bf, FF * DD / 4);
        k_conv<<<2304, 256, 0, stream>>>(W2 + (size_t)l * DD * FF, W2_bf, FF * DD / 4);
        k_gemm_bf<1><<<dim3(FF / 128, MPAD / 128), 256, 0, stream>>>(
            h_bf, W1_bf, b1 + (size_t)l * FF, mlp_bf, NTOK, FF, DD);
        k_gemm_bf<2><<<dim3(DD / 128, MPAD / 128), 256, 0, stream>>>(
            mlp_bf, W2_bf, b2 + (size_t)l * DD, x, NTOK, DD, FF);
    }

    k_head<<<dim3(4, BB), 256, 0, stream>>>(x, Wh, bh, out);
}

// Round 5
// 2934.968 us; speedup vs baseline: 9.3184x; 1.0537x over previous
//
#include <hip/hip_runtime.h>
#include <math.h>

// ---- problem constants ----
#define BB 32
#define SS 197
#define DD 768
#define HH 12
#define DHD 64
#define LL 12
#define FF 3072
#define NPATCH 196
#define NTOK (BB * SS)          // 6304
#define MPAD 6400               // NTOK padded to multiple of 128
#define LNEPS 1e-5f

typedef short bf8_t __attribute__((ext_vector_type(8)));
typedef float f4_t  __attribute__((ext_vector_type(4)));
typedef unsigned short u16x8 __attribute__((ext_vector_type(8)));

__device__ __forceinline__ unsigned short f2bf(float x) {
    unsigned u = __float_as_uint(x);
    return (unsigned short)((u + 0x8000u) >> 16);
}
__device__ __forceinline__ float bf_lo(unsigned u) { return __uint_as_float(u << 16); }

__device__ __forceinline__ void gl_lds16(const void* g, void* l) {
    __builtin_amdgcn_global_load_lds((const __attribute__((address_space(1))) unsigned int*)g,
                                     (__attribute__((address_space(3))) unsigned int*)l, 16, 0, 0);
}

// =====================================================================
// fp32 -> bf16 converters
// =====================================================================
__global__ __launch_bounds__(256) void k_conv(const float* __restrict__ a,
                                              unsigned short* __restrict__ o, int n4) {
    for (int i = blockIdx.x * 256 + threadIdx.x; i < n4; i += gridDim.x * 256) {
        float4 v = ((const float4*)a)[i];
        ushort4 r;
        r.x = f2bf(v.x); r.y = f2bf(v.y); r.z = f2bf(v.z); r.w = f2bf(v.w);
        ((ushort4*)o)[i] = r;
    }
}

// two tensors in one launch (per-layer W1+W2)
__global__ __launch_bounds__(256) void k_conv2(const float* __restrict__ a1,
                                               unsigned short* __restrict__ o1, int n1,
                                               const float* __restrict__ a2,
                                               unsigned short* __restrict__ o2, int n2) {
    for (int i = blockIdx.x * 256 + threadIdx.x; i < n1 + n2; i += gridDim.x * 256) {
        const float* a = (i < n1) ? a1 : a2;
        unsigned short* o = (i < n1) ? o1 : o2;
        int j = (i < n1) ? i : i - n1;
        float4 v = ((const float4*)a)[j];
        ushort4 r;
        r.x = f2bf(v.x); r.y = f2bf(v.y); r.z = f2bf(v.z); r.w = f2bf(v.w);
        ((ushort4*)o)[j] = r;
    }
}

// =====================================================================
// patchify: image [B,3,224,224] -> P_bf [B*196, 768] bf16, order (c,pi,pj)
// =====================================================================
__global__ __launch_bounds__(256) void k_patchify(const float* __restrict__ img,
                                                  unsigned short* __restrict__ P) {
    const int total = BB * NPATCH * DD;
    for (int idx = blockIdx.x * 256 + threadIdx.x; idx < total; idx += gridDim.x * 256) {
        int e = idx % DD;
        int rest = idx / DD;
        int p = rest % NPATCH;
        int b = rest / NPATCH;
        int c = e >> 8;
        int pi = (e >> 4) & 15;
        int pj = e & 15;
        int i = p / 14, j = p % 14;
        P[idx] = f2bf(img[(((size_t)b * 3 + c) * 224 + (i * 16 + pi)) * 224 + (j * 16 + pj)]);
    }
}

// =====================================================================
// bf16 MFMA GEMM (m97 structure): C[m,n] = A[m,k] * W[n,k]^T + bias
// EPI: 0 = embed (remap rows, f32 store), 1 = GELU -> bf16, 2 = res add f32
// =====================================================================
template <int EPI>
__global__ __launch_bounds__(256) void k_gemm_bf(const unsigned short* __restrict__ A,
                                                 const unsigned short* __restrict__ Bw,
                                                 const float* __restrict__ bias,
                                                 void* __restrict__ Cout,
                                                 int M, int N, int K) {
    __shared__ unsigned short As[128 * 32];
    __shared__ unsigned short Bs[128 * 32];
    const int tid = threadIdx.x;
    const int wave = tid >> 6, lane = tid & 63;
    const int m0 = blockIdx.y << 7, n0 = blockIdx.x << 7;

    const int r0 = tid >> 2, kp = (tid & 3) * 8;
    const unsigned short* gA0 = A + (size_t)(m0 + r0) * K + kp;
    const unsigned short* gA1 = A + (size_t)(m0 + 64 + r0) * K + kp;
    const unsigned short* gB0 = Bw + (size_t)(n0 + r0) * K + kp;
    const unsigned short* gB1 = Bw + (size_t)(n0 + 64 + r0) * K + kp;
    unsigned short* lA0 = &As[tid * 8];
    unsigned short* lA1 = &As[(tid + 256) * 8];
    unsigned short* lB0 = &Bs[tid * 8];
    unsigned short* lB1 = &Bs[(tid + 256) * 8];

    const int mh = (wave >> 1) << 6, nh = (wave & 1) << 6;
    const int lm = lane & 15, kq = lane >> 4;

    f4_t acc[4][4];
#pragma unroll
    for (int i = 0; i < 4; ++i)
#pragma unroll
        for (int j = 0; j < 4; ++j) acc[i][j] = (f4_t){0.f, 0.f, 0.f, 0.f};

    for (int k0 = 0; k0 < K; k0 += 32) {
        gl_lds16(gA0, lA0);
        gl_lds16(gA1, lA1);
        gl_lds16(gB0, lB0);
        gl_lds16(gB1, lB1);
        gA0 += 32; gA1 += 32; gB0 += 32; gB1 += 32;
        __syncthreads();
        bf8_t af[4], bfr[4];
#pragma unroll
        for (int mt = 0; mt < 4; ++mt)
            af[mt] = *(const bf8_t*)&As[(mh + mt * 16 + lm) * 32 + kq * 8];
#pragma unroll
        for (int nt = 0; nt < 4; ++nt)
            bfr[nt] = *(const bf8_t*)&Bs[(nh + nt * 16 + lm) * 32 + kq * 8];
#pragma unroll
        for (int mt = 0; mt < 4; ++mt)
#pragma unroll
            for (int nt = 0; nt < 4; ++nt)
                acc[mt][nt] = __builtin_amdgcn_mfma_f32_16x16x32_bf16(af[mt], bfr[nt],
                                                                      acc[mt][nt], 0, 0, 0);
        __syncthreads();
    }

    const int rbase = m0 + mh + kq * 4;
    const int cbase = n0 + nh + lm;
#pragma unroll
    for (int mt = 0; mt < 4; ++mt) {
#pragma unroll
        for (int nt = 0; nt < 4; ++nt) {
            const int col = cbase + nt * 16;
            const float bv = bias[col];
#pragma unroll
            for (int r = 0; r < 4; ++r) {
                const int row = rbase + mt * 16 + r;
                float val = acc[mt][nt][r] + bv;
                if (EPI == 0) {
                    size_t om = (size_t)(row / 196) * 197 + (row % 196) + 1;
                    ((float*)Cout)[om * DD + col] = val;
                } else if (EPI == 1) {
                    val = 0.5f * val * (1.f + erff(val * 0.7071067811865476f));
                    ((unsigned short*)Cout)[(size_t)row * N + col] = f2bf(val);
                } else {
                    if (row < M) ((float*)Cout)[(size_t)row * DD + col] += val;
                }
            }
        }
    }
}

// =====================================================================
// split-K bf16 MFMA GEMM for skinny-N: residual-add epilogue via atomics.
// grid (N/128, M/128, SPLIT); chunk z reduces K-range [z*K/S, (z+1)*K/S);
// bias added by z==0 only.
// =====================================================================
__global__ __launch_bounds__(256) void k_gemm_sk(const unsigned short* __restrict__ A,
                                                 const unsigned short* __restrict__ Bw,
                                                 const float* __restrict__ bias,
                                                 float* __restrict__ Cout,
                                                 int M, int N, int K) {
    __shared__ unsigned short As[128 * 32];
    __shared__ unsigned short Bs[128 * 32];
    const int tid = threadIdx.x;
    const int wave = tid >> 6, lane = tid & 63;
    const int m0 = blockIdx.y << 7, n0 = blockIdx.x << 7;
    const int ksplit = K / gridDim.z;
    const int kbeg = blockIdx.z * ksplit;

    const int r0 = tid >> 2, kp = (tid & 3) * 8;
    const unsigned short* gA0 = A + (size_t)(m0 + r0) * K + kbeg + kp;
    const unsigned short* gA1 = A + (size_t)(m0 + 64 + r0) * K + kbeg + kp;
    const unsigned short* gB0 = Bw + (size_t)(n0 + r0) * K + kbeg + kp;
    const unsigned short* gB1 = Bw + (size_t)(n0 + 64 + r0) * K + kbeg + kp;
    unsigned short* lA0 = &As[tid * 8];
    unsigned short* lA1 = &As[(tid + 256) * 8];
    unsigned short* lB0 = &Bs[tid * 8];
    unsigned short* lB1 = &Bs[(tid + 256) * 8];

    const int mh = (wave >> 1) << 6, nh = (wave & 1) << 6;
    const int lm = lane & 15, kq = lane >> 4;

    f4_t acc[4][4];
#pragma unroll
    for (int i = 0; i < 4; ++i)
#pragma unroll
        for (int j = 0; j < 4; ++j) acc[i][j] = (f4_t){0.f, 0.f, 0.f, 0.f};

    for (int k0 = 0; k0 < ksplit; k0 += 32) {
        gl_lds16(gA0, lA0);
        gl_lds16(gA1, lA1);
        gl_lds16(gB0, lB0);
        gl_lds16(gB1, lB1);
        gA0 += 32; gA1 += 32; gB0 += 32; gB1 += 32;
        __syncthreads();
        bf8_t af[4], bfr[4];
#pragma unroll
        for (int mt = 0; mt < 4; ++mt)
            af[mt] = *(const bf8_t*)&As[(mh + mt * 16 + lm) * 32 + kq * 8];
#pragma unroll
        for (int nt = 0; nt < 4; ++nt)
            bfr[nt] = *(const bf8_t*)&Bs[(nh + nt * 16 + lm) * 32 + kq * 8];
#pragma unroll
        for (int mt = 0; mt < 4; ++mt)
#pragma unroll
            for (int nt = 0; nt < 4; ++nt)
                acc[mt][nt] = __builtin_amdgcn_mfma_f32_16x16x32_bf16(af[mt], bfr[nt],
                                                                      acc[mt][nt], 0, 0, 0);
        __syncthreads();
    }

    const int rbase = m0 + mh + kq * 4;
    const int cbase = n0 + nh + lm;
    const bool addb = (blockIdx.z == 0);
#pragma unroll
    for (int mt = 0; mt < 4; ++mt) {
#pragma unroll
        for (int nt = 0; nt < 4; ++nt) {
            const int col = cbase + nt * 16;
            const float bv = addb ? bias[col] : 0.f;
#pragma unroll
            for (int r = 0; r < 4; ++r) {
                const int row = rbase + mt * 16 + r;
                if (row < M)
                    unsafeAtomicAdd(&Cout[(size_t)row * DD + col], acc[mt][nt][r] + bv);
            }
        }
    }
}

// =====================================================================
// QKV via MFMA: block = (head, 128-token tile). Single-barrier K=64.
// =====================================================================
__global__ __launch_bounds__(256) void k_qkv_mfma(const unsigned short* __restrict__ h,
                                                  const unsigned short* __restrict__ Wqb,
                                                  const unsigned short* __restrict__ Wkb,
                                                  const unsigned short* __restrict__ Wvb,
                                                  const float* __restrict__ bq,
                                                  const float* __restrict__ bk,
                                                  const float* __restrict__ bv,
                                                  unsigned short* __restrict__ qo,
                                                  unsigned short* __restrict__ ko,
                                                  unsigned short* __restrict__ vo) {
    __shared__ unsigned short As[2 * 128 * 32];       // [khalf][row][32]
    __shared__ unsigned short Bs[3 * 2 * 64 * 32];    // [mat][khalf][row][32]
    const int head = blockIdx.x;
    const int m0 = blockIdx.y << 7;
    const int tid = threadIdx.x;
    const int wave = tid >> 6, lane = tid & 63;
    const int lm = lane & 15, kq = lane >> 4;

#pragma unroll
    for (int j = 0; j < 4; ++j) {
        int khalf = j >> 1;
        int rem = (j & 1) * 256 + tid;           // 0..511
        int row = rem >> 2, koff = (rem & 3) * 8;
        gl_lds16(h + (size_t)(m0 + row) * DD + head * 64 + khalf * 32 + koff,
                 &As[(j * 256 + tid) * 8]);
    }
    const unsigned short* Wq_h = Wqb + head * 4096;
    const unsigned short* Wk_h = Wkb + head * 4096;
    const unsigned short* Wv_h = Wvb + head * 4096;
#pragma unroll
    for (int j = 0; j < 6; ++j) {
        const unsigned short* src = (j < 2) ? Wq_h : ((j < 4) ? Wk_h : Wv_h);
        int cm = (j & 1) * 256 + tid;            // 0..511 within mat
        int khalf = cm >> 8;
        int rem2 = cm & 255;
        int row = rem2 >> 2, koff = (rem2 & 3) * 8;
        gl_lds16(src + row * 64 + khalf * 32 + koff, &Bs[(j * 256 + tid) * 8]);
    }
    __syncthreads();

    f4_t acc[2][12];
#pragma unroll
    for (int i = 0; i < 2; ++i)
#pragma unroll
        for (int j = 0; j < 12; ++j) acc[i][j] = (f4_t){0.f, 0.f, 0.f, 0.f};

#pragma unroll
    for (int kh = 0; kh < 2; ++kh) {
        bf8_t af[2], bfr[12];
#pragma unroll
        for (int mt = 0; mt < 2; ++mt)
            af[mt] = *(const bf8_t*)&As[kh * 4096 + (wave * 32 + mt * 16 + lm) * 32 + kq * 8];
#pragma unroll
        for (int nt = 0; nt < 12; ++nt)
            bfr[nt] = *(const bf8_t*)&Bs[(nt >> 2) * 4096 + kh * 2048 +
                                         ((nt & 3) * 16 + lm) * 32 + kq * 8];
#pragma unroll
        for (int mt = 0; mt < 2; ++mt)
#pragma unroll
            for (int nt = 0; nt < 12; ++nt)
                acc[mt][nt] = __builtin_amdgcn_mfma_f32_16x16x32_bf16(af[mt], bfr[nt],
                                                                      acc[mt][nt], 0, 0, 0);
    }

    const int rbase = m0 + wave * 32 + kq * 4;
#pragma unroll
    for (int mt = 0; mt < 2; ++mt) {
#pragma unroll
        for (int nt = 0; nt < 12; ++nt) {
            const int col = nt * 16 + lm;
            const int e = col & 63;
            const float* bsrc = (nt < 4) ? bq : ((nt < 8) ? bk : bv);
            unsigned short* dst = (nt < 4) ? qo : ((nt < 8) ? ko : vo);
            const float bval = bsrc[head * 64 + e];
#pragma unroll
            for (int r = 0; r < 4; ++r) {
                const int row = rbase + mt * 16 + r;
                if (row < NTOK)
                    dst[(size_t)row * DD + head * 64 + e] = f2bf(acc[mt][nt][r] + bval);
            }
        }
    }
}

// =====================================================================
// pos-embed add (+cls for s==0)
// =====================================================================
__global__ __launch_bounds__(256) void k_posadd(float* __restrict__ x,
                                                const float* __restrict__ cls) {
    const int total = BB * SS * DD;
    const float LN1E4 = 9.210340371976184f;
    for (int idx = blockIdx.x * 256 + threadIdx.x; idx < total; idx += gridDim.x * 256) {
        int d = idx % DD;
        int s = (idx / DD) % SS;
        float ang = (float)s * __expf(-LN1E4 * (float)(2 * (d >> 1)) / 768.f);
        float pv = (d & 1) ? __cosf(ang) : __sinf(ang);
        if (s == 0) x[idx] = cls[d] + pv;
        else        x[idx] += pv;
    }
}

// =====================================================================
// LayerNorm: wave per row (4 rows/block), lane holds 12 elems, bf16 out
// =====================================================================
__global__ __launch_bounds__(256) void k_ln2(const float* __restrict__ x,
                                             const float* __restrict__ g,
                                             const float* __restrict__ bp,
                                             unsigned short* __restrict__ out) {
    const int row = blockIdx.x * 4 + (threadIdx.x >> 6);
    const int lane = threadIdx.x & 63;
    if (row >= NTOK) return;
    const float* xr = x + (size_t)row * DD + lane * 12;
    float4 a = ((const float4*)xr)[0];
    float4 b = ((const float4*)xr)[1];
    float4 c = ((const float4*)xr)[2];
    float s = a.x + a.y + a.z + a.w + b.x + b.y + b.z + b.w + c.x + c.y + c.z + c.w;
#pragma unroll
    for (int o = 32; o; o >>= 1) s += __shfl_xor(s, o);
    const float mean = s * (1.f / DD);
    float vr = 0.f, e0;
    e0 = a.x - mean; vr += e0 * e0; e0 = a.y - mean; vr += e0 * e0;
    e0 = a.z - mean; vr += e0 * e0; e0 = a.w - mean; vr += e0 * e0;
    e0 = b.x - mean; vr += e0 * e0; e0 = b.y - mean; vr += e0 * e0;
    e0 = b.z - mean; vr += e0 * e0; e0 = b.w - mean; vr += e0 * e0;
    e0 = c.x - mean; vr += e0 * e0; e0 = c.y - mean; vr += e0 * e0;
    e0 = c.z - mean; vr += e0 * e0; e0 = c.w - mean; vr += e0 * e0;
#pragma unroll
    for (int o = 32; o; o >>= 1) vr += __shfl_xor(vr, o);
    const float rstd = rsqrtf(vr * (1.f / DD) + LNEPS);

    const float4* g4 = (const float4*)(g + lane * 12);
    const float4* b4p = (const float4*)(bp + lane * 12);
    unsigned short* op = out + (size_t)row * DD + lane * 12;
    float4 gv, bv;
    ushort4 r;
    gv = g4[0]; bv = b4p[0];
    r.x = f2bf((a.x - mean) * rstd * gv.x + bv.x);
    r.y = f2bf((a.y - mean) * rstd * gv.y + bv.y);
    r.z = f2bf((a.z - mean) * rstd * gv.z + bv.z);
    r.w = f2bf((a.w - mean) * rstd * gv.w + bv.w);
    ((ushort4*)op)[0] = r;
    gv = g4[1]; bv = b4p[1];
    r.x = f2bf((b.x - mean) * rstd * gv.x + bv.x);
    r.y = f2bf((b.y - mean) * rstd * gv.y + bv.y);
    r.z = f2bf((b.z - mean) * rstd * gv.z + bv.z);
    r.w = f2bf((b.w - mean) * rstd * gv.w + bv.w);
    ((ushort4*)op)[1] = r;
    gv = g4[2]; bv = b4p[2];
    r.x = f2bf((c.x - mean) * rstd * gv.x + bv.x);
    r.y = f2bf((c.y - mean) * rstd * gv.y + bv.y);
    r.z = f2bf((c.z - mean) * rstd * gv.z + bv.z);
    r.w = f2bf((c.w - mean) * rstd * gv.w + bv.w);
    ((ushort4*)op)[2] = r;
}

// =====================================================================
// attention v3 (MFMA): block = (64-query tile, head, b), 256 thr = 4 waves.
// =====================================================================
__global__ __launch_bounds__(256) void k_attn3(const unsigned short* __restrict__ qg,
                                               const unsigned short* __restrict__ kg,
                                               const unsigned short* __restrict__ vg,
                                               float* __restrict__ x) {
    const int qt = blockIdx.x, head = blockIdx.y, b = blockIdx.z;
    const int tid = threadIdx.x, wv = tid >> 6, lane = tid & 63;
    const int lm = lane & 15, kq = lane >> 4;

    __shared__ __align__(16) unsigned short lds[29696];   // 59392 B
    unsigned short* Kl = lds;            // [kh][224][32] = 14336 sh
    unsigned short* Pl = lds;            // [4][16][232]  = 14848 sh (aliases K)
    unsigned short* Vt = lds + 14848;    // [64][232]     = 14848 sh

    const size_t tokbase = (size_t)b * SS;
    const unsigned short* kb = kg + tokbase * DD + head * 64;
    const unsigned short* vb = vg + tokbase * DD + head * 64;
    const unsigned short* qb = qg + tokbase * DD + head * 64;

    // ---- stage K: [kh][t(224)][32], 1792 x 16B chunks via global_load_lds ----
#pragma unroll
    for (int it = 0; it < 7; ++it) {
        int c = it * 256 + tid;
        int kh = c / 896, rem = c - kh * 896;
        int t = rem >> 2, cc = rem & 3;
        gl_lds16(kb + (size_t)t * DD + kh * 32 + cc * 8, (char*)lds + c * 16);
    }
    // ---- stage V transposed: Vt[e][t], t padded 224 (197.. zeroed) ----
#pragma unroll
    for (int it = 0; it < 7; ++it) {
        int idx = it * 256 + tid;
        int t = idx >> 3, eg = idx & 7;
        if (t < SS) {
            u16x8 v8 = *(const u16x8*)(vb + (size_t)t * DD + eg * 8);
#pragma unroll
            for (int j = 0; j < 8; ++j) Vt[(eg * 8 + j) * 232 + t] = v8[j];
        } else {
#pragma unroll
            for (int j = 0; j < 8; ++j) Vt[(eg * 8 + j) * 232 + t] = 0;
        }
    }

    // ---- Q fragments (B-operand) straight from global ----
    const int qrow = qt * 64 + wv * 16 + lm;
    bf8_t qf0 = *(const bf8_t*)(qb + (size_t)qrow * DD + kq * 8);
    bf8_t qf1 = *(const bf8_t*)(qb + (size_t)qrow * DD + 32 + kq * 8);

    __syncthreads();

    // ---- S^T: D[t-tile][q16] ; 13 t-tiles x 2 kh ----
    f4_t sacc[13];
#pragma unroll
    for (int tt = 0; tt < 13; ++tt) sacc[tt] = (f4_t){0.f, 0.f, 0.f, 0.f};
#pragma unroll
    for (int tt = 0; tt < 13; ++tt) {
        bf8_t a0 = *(const bf8_t*)&Kl[(tt * 16 + lm) * 32 + kq * 8];
        bf8_t a1 = *(const bf8_t*)&Kl[7168 + (tt * 16 + lm) * 32 + kq * 8];
        sacc[tt] = __builtin_amdgcn_mfma_f32_16x16x32_bf16(a0, qf0, sacc[tt], 0, 0, 0);
        sacc[tt] = __builtin_amdgcn_mfma_f32_16x16x32_bf16(a1, qf1, sacc[tt], 0, 0, 0);
    }

    // ---- softmax over t for q = lm ----
    float mx = -1e30f;
#pragma unroll
    for (int tt = 0; tt < 13; ++tt)
#pragma unroll
        for (int r = 0; r < 4; ++r) {
            float s = sacc[tt][r] * 0.125f;
            if (tt == 12 && (kq * 4 + r) >= 5) s = -1e30f;   // t >= 197
            sacc[tt][r] = s;
            mx = fmaxf(mx, s);
        }
    mx = fmaxf(mx, __shfl_xor(mx, 16));
    mx = fmaxf(mx, __shfl_xor(mx, 32));
    float sum = 0.f;
#pragma unroll
    for (int tt = 0; tt < 13; ++tt)
#pragma unroll
        for (int r = 0; r < 4; ++r) {
            float p = __expf(sacc[tt][r] - mx);
            sacc[tt][r] = p;
            sum += p;
        }
    sum += __shfl_xor(sum, 16);
    sum += __shfl_xor(sum, 32);
    const float inv = 1.f / sum;

    __syncthreads();   // all waves done reading K -> safe to overwrite with P

    // ---- write P (A-layout rows [q][t], per-wave region) ----
    unsigned short* Pw = Pl + wv * 3712;
#pragma unroll
    for (int tt = 0; tt < 13; ++tt)
#pragma unroll
        for (int r = 0; r < 4; ++r)
            Pw[lm * 232 + tt * 16 + kq * 4 + r] = f2bf(sacc[tt][r]);
    *(short4*)&Pw[lm * 232 + 208 + kq * 4] = make_short4(0, 0, 0, 0);

    // ---- PV: O[q][e] ; 7 k-chunks x 4 e-tiles ----
    f4_t oacc[4];
#pragma unroll
    for (int et = 0; et < 4; ++et) oacc[et] = (f4_t){0.f, 0.f, 0.f, 0.f};
#pragma unroll
    for (int kc = 0; kc < 7; ++kc) {
        bf8_t pa = *(const bf8_t*)&Pw[lm * 232 + kc * 32 + kq * 8];
#pragma unroll
        for (int et = 0; et < 4; ++et) {
            bf8_t vv = *(const bf8_t*)&Vt[(et * 16 + lm) * 232 + kc * 32 + kq * 8];
            oacc[et] = __builtin_amdgcn_mfma_f32_16x16x32_bf16(pa, vv, oacc[et], 0, 0, 0);
        }
    }

    // ---- 1/sum redistribution (softmax layout q=lm -> C layout q=kq*4+r) ----
    float invq[4];
#pragma unroll
    for (int r = 0; r < 4; ++r) invq[r] = __shfl(inv, kq * 4 + r);

    // ---- residual add into x ----
    float* xp = x + tokbase * DD + head * 64;
#pragma unroll
    for (int r = 0; r < 4; ++r) {
        const int qgr = qt * 64 + wv * 16 + kq * 4 + r;
        if (qgr < SS) {
#pragma unroll
            for (int et = 0; et < 4; ++et)
                xp[(size_t)qgr * DD + et * 16 + lm] += oacc[et][r] * invq[r];
        }
    }
}

// =====================================================================
// classifier head (fp32)
// =====================================================================
__global__ __launch_bounds__(256) void k_head(const float* __restrict__ x,
                                              const float* __restrict__ Wh,
                                              const float* __restrict__ bh,
                                              float* __restrict__ out) {
    const int b = blockIdx.y;
    const int c = blockIdx.x * 256 + threadIdx.x;
    __shared__ __align__(16) float xs[DD];
    const float* xr = x + (size_t)b * SS * DD;
    for (int d = threadIdx.x; d < DD; d += 256) xs[d] = xr[d];
    __syncthreads();
    if (c < 1000) {
        const float4* w4 = (const float4*)(Wh + (size_t)c * DD);
        float acc = 0.f;
#pragma unroll 4
        for (int d4 = 0; d4 < DD / 4; ++d4) {
            float4 w = w4[d4];
            const float4 xv = *(const float4*)&xs[d4 << 2];
            acc += xv.x * w.x + xv.y * w.y + xv.z * w.z + xv.w * w.w;
        }
        out[(size_t)b * 1000 + c] = acc + bh[c];
    }
}

// =====================================================================
extern "C" void kernel_launch(void* const* d_in, const int* in_sizes, int n_in,
                              void* d_out, int out_size, void* d_ws, size_t ws_size,
                              hipStream_t stream) {
    const float* image   = (const float*)d_in[0];
    const float* W_embed = (const float*)d_in[1];
    const float* b_embed = (const float*)d_in[2];
    const float* cls     = (const float*)d_in[3];
    const float* Wq      = (const float*)d_in[4];
    const float* bq      = (const float*)d_in[5];
    const float* Wk      = (const float*)d_in[6];
    const float* bk      = (const float*)d_in[7];
    const float* Wv      = (const float*)d_in[8];
    const float* bv      = (const float*)d_in[9];
    const float* ln1g    = (const float*)d_in[10];
    const float* ln1b    = (const float*)d_in[11];
    const float* ln2g    = (const float*)d_in[12];
    const float* ln2b    = (const float*)d_in[13];
    const float* W1      = (const float*)d_in[14];
    const float* b1      = (const float*)d_in[15];
    const float* W2      = (const float*)d_in[16];
    const float* b2      = (const float*)d_in[17];
    const float* Wh      = (const float*)d_in[18];
    const float* bh      = (const float*)d_in[19];
    float* out = (float*)d_out;

    float* x = (float*)d_ws;
    unsigned short* h_bf   = (unsigned short*)(x + (size_t)NTOK * DD);
    unsigned short* q_bf   = h_bf + (size_t)MPAD * DD;
    unsigned short* k_bf   = q_bf + (size_t)MPAD * DD;
    unsigned short* v_bf   = k_bf + (size_t)MPAD * DD;
    unsigned short* mlp_bf = v_bf + (size_t)MPAD * DD;            // MPAD*FF
    unsigned short* W1_bf  = mlp_bf + (size_t)MPAD * FF;
    unsigned short* W2_bf  = W1_bf + (size_t)FF * DD;
    unsigned short* We_bf  = W2_bf + (size_t)FF * DD;
    unsigned short* Wq_bf  = We_bf + (size_t)DD * DD;             // L*H*64*64
    unsigned short* Wk_bf  = Wq_bf + (size_t)LL * HH * DHD * DHD;
    unsigned short* Wv_bf  = Wk_bf + (size_t)LL * HH * DHD * DHD;
    unsigned short* P_bf   = mlp_bf;                              // alias pre-loop

    const int QKVW = LL * HH * DHD * DHD;                         // 589824

    // one-time weight conversions
    k_conv<<<576, 256, 0, stream>>>(W_embed, We_bf, DD * DD / 4);
    k_conv<<<576, 256, 0, stream>>>(Wq, Wq_bf, QKVW / 4);
    k_conv<<<576, 256, 0, stream>>>(Wk, Wk_bf, QKVW / 4);
    k_conv<<<576, 256, 0, stream>>>(Wv, Wv_bf, QKVW / 4);

    // embed
    k_patchify<<<1024, 256, 0, stream>>>(image, P_bf);
    k_gemm_bf<0><<<dim3(6, 49), 256, 0, stream>>>(P_bf, We_bf, b_embed, x,
                                                  BB * NPATCH, DD, DD);
    k_posadd<<<1024, 256, 0, stream>>>(x, cls);

    for (int l = 0; l < LL; ++l) {
        k_ln2<<<(NTOK + 3) / 4, 256, 0, stream>>>(x, ln1g + l * DD, ln1b + l * DD, h_bf);
        k_qkv_mfma<<<dim3(HH, MPAD / 128), 256, 0, stream>>>(
            h_bf, Wq_bf + (size_t)l * HH * 4096, Wk_bf + (size_t)l * HH * 4096,
            Wv_bf + (size_t)l * HH * 4096, bq + l * DD, bk + l * DD, bv + l * DD,
            q_bf, k_bf, v_bf);
        k_attn3<<<dim3(4, HH, BB), 256, 0, stream>>>(q_bf, k_bf, v_bf, x);
        k_ln2<<<(NTOK + 3) / 4, 256, 0, stream>>>(x, ln2g + l * DD, ln2b + l * DD, h_bf);
        k_conv2<<<2048, 256, 0, stream>>>(W1 + (size_t)l * FF * DD, W1_bf, FF * DD / 4,
                                          W2 + (size_t)l * DD * FF, W2_bf, FF * DD / 4);
        k_gemm_bf<1><<<dim3(FF / 128, MPAD / 128), 256, 0, stream>>>(
            h_bf, W1_bf, b1 + (size_t)l * FF, mlp_bf, NTOK, FF, DD);
        k_gemm_sk<<<dim3(DD / 128, MPAD / 128, 2), 256, 0, stream>>>(
            mlp_bf, W2_bf, b2 + (size_t)l * DD, x, NTOK, DD, FF);
    }

    k_head<<<dim3(4, BB), 256, 0, stream>>>(x, Wh, bh, out);
}